// Round 3
// baseline (596.843 us; speedup 1.0000x reference)
//
#include <hip/hip_runtime.h>
#include <hip/hip_bf16.h>
#include <stdint.h>

typedef unsigned short u16;
typedef __attribute__((ext_vector_type(8))) short short8;   // 8 bf16 (4 VGPRs) MFMA A/B frag
typedef __attribute__((ext_vector_type(4))) float f32x4;    // MFMA C/D frag
typedef __attribute__((ext_vector_type(4))) unsigned short u16x4;

#define DEV static __device__ __forceinline__

// B=4, S=2048, D=1024, H=16, DK=64, DOUT=1024; M = B*S = 8192

DEV u16 f2bf(float f) {  // f32 -> bf16 RNE (compiler emits v_cvt_pk_bf16_f32 for pairs)
  __hip_bfloat16 b = __float2bfloat16(f);
  return *(u16*)&b;
}

DEV void stage16(const u16* g, u16* l) {
  // async global->LDS, 16B per lane; LDS dest = wave-uniform base + lane*16
  __builtin_amdgcn_global_load_lds((const __attribute__((address_space(1))) void*)g,
                                   (__attribute__((address_space(3))) void*)l, 16, 0, 0);
}

// ---------------- conversions / transposes (one launch) ----------------
__global__ __launch_bounds__(256) void cvt_kernel(
    const float* __restrict__ x, const float* __restrict__ Wq,
    const float* __restrict__ Wk, const float* __restrict__ Wv,
    const float* __restrict__ Wo,
    u16* __restrict__ xb, u16* __restrict__ Wt, u16* __restrict__ Wot)
{
  int idx = blockIdx.x * 256 + threadIdx.x;
  if (idx < 1048576) {                      // x: [8192][1024] f32 -> bf16, 8 elems/thread
    int i = idx * 8;
    f32x4 v0 = *(const f32x4*)&x[i];
    f32x4 v1 = *(const f32x4*)&x[i + 4];
    short8 o;
    o[0]=f2bf(v0[0]); o[1]=f2bf(v0[1]); o[2]=f2bf(v0[2]); o[3]=f2bf(v0[3]);
    o[4]=f2bf(v1[0]); o[5]=f2bf(v1[1]); o[6]=f2bf(v1[2]); o[7]=f2bf(v1[3]);
    *(short8*)&xb[i] = o;
  } else if (idx < 1835008) {               // Wq/Wk/Wv [H][D][DK] -> Wt[w][n=h*64+k][d]
    int t = (idx - 1048576) * 4;
    int w = t >> 20; int r = t & 1048575; int n = r >> 10; int d0 = r & 1023;
    const float* W = (w == 0) ? Wq : (w == 1) ? Wk : Wv;
    int h = n >> 6, k = n & 63;
    u16x4 o;
    #pragma unroll
    for (int u = 0; u < 4; u++) o[u] = f2bf(W[(size_t)(h*1024 + d0 + u)*64 + k]);
    *(u16x4*)&Wt[t] = o;
  } else if (idx < 2097152) {               // Wo [f][n] -> Wot[n][f]
    int t = (idx - 1835008) * 4;
    int n = t >> 10, d0 = t & 1023;
    u16x4 o;
    #pragma unroll
    for (int u = 0; u < 4; u++) o[u] = f2bf(Wo[(size_t)(d0 + u)*1024 + n]);
    *(u16x4*)&Wot[t] = o;
  }
}

// ---------------- shared GEMM main loop (128x128 tile, BK=32, 4 waves) ----------------
DEV void gemm_mainloop(const u16* __restrict__ A, const u16* __restrict__ Bt,
                       int m0, int n0, u16* As, u16* Bs, f32x4 acc[4][4])
{
  const int tid = threadIdx.x;
  const int lane = tid & 63, wid = tid >> 6;
  const int wr = wid >> 1, wc = wid & 1;
  const int qr = lane & 15, g = lane >> 4;
  const int c0 = wid * 2, rA = lane >> 2, cA = (lane & 3) * 8;

  #pragma unroll
  for (int i = 0; i < 4; i++)
    #pragma unroll
    for (int j = 0; j < 4; j++) acc[i][j] = (f32x4){0.f, 0.f, 0.f, 0.f};

  for (int kt = 0; kt < 1024; kt += 32) {
    #pragma unroll
    for (int q = 0; q < 2; q++) {
      const int c = c0 + q;                 // chunk of 16 rows (1KB LDS)
      stage16(A  + (size_t)(m0 + c*16 + rA)*1024 + kt + cA, &As[c*512]);
      stage16(Bt + (size_t)(n0 + c*16 + rA)*1024 + kt + cA, &Bs[c*512]);
    }
    __syncthreads();
    short8 af[4], bfr[4];
    #pragma unroll
    for (int i = 0; i < 4; i++) af[i]  = *(const short8*)&As[(wr*64 + i*16 + qr)*32 + g*8];
    #pragma unroll
    for (int j = 0; j < 4; j++) bfr[j] = *(const short8*)&Bs[(wc*64 + j*16 + qr)*32 + g*8];
    #pragma unroll
    for (int i = 0; i < 4; i++)
      #pragma unroll
      for (int j = 0; j < 4; j++)
        acc[i][j] = __builtin_amdgcn_mfma_f32_16x16x32_bf16(af[i], bfr[j], acc[i][j], 0, 0, 0);
    __syncthreads();
  }
}

// ---------------- QKV projection: z picks Q/K/V ----------------
__global__ __launch_bounds__(256) void qkv_gemm_kernel(
    const u16* __restrict__ A, const u16* __restrict__ WtAll,
    const float* __restrict__ bq, const float* __restrict__ bk, const float* __restrict__ bv,
    u16* __restrict__ Qo, u16* __restrict__ Ko, u16* __restrict__ Vo)
{
  __shared__ __align__(128) u16 As[4096];
  __shared__ __align__(128) u16 Bs[4096];
  const int lane = threadIdx.x & 63, wid = threadIdx.x >> 6;
  const int wr = wid >> 1, wc = wid & 1;
  const int qr = lane & 15, g = lane >> 4;
  const int m0 = blockIdx.y * 128, n0 = blockIdx.x * 128;
  const int mode = blockIdx.z;
  const u16* Bt = WtAll + (size_t)mode * 1048576;
  const float* bias = (mode == 0) ? bq : (mode == 1) ? bk : bv;

  f32x4 acc[4][4];
  gemm_mainloop(A, Bt, m0, n0, As, Bs, acc);

  if (mode == 2) {
    // V transposed: Vt[b][h][dk][s], 4 consecutive s per lane -> 8B store
    #pragma unroll
    for (int i = 0; i < 4; i++) {
      const int mrow = m0 + wr*64 + i*16 + g*4;
      const int b = mrow >> 11, s = mrow & 2047;
      #pragma unroll
      for (int j = 0; j < 4; j++) {
        const int n = n0 + wc*64 + j*16 + qr;
        const float bz = bias[n];
        u16x4 v;
        #pragma unroll
        for (int r = 0; r < 4; r++) v[r] = f2bf(acc[i][j][r] + bz);
        *(u16x4*)&Vo[((size_t)(b*16 + (n >> 6))*64 + (n & 63))*2048 + s] = v;
      }
    }
  } else {
    u16* O = (mode == 0) ? Qo : Ko;         // [b][h][s][dk]
    #pragma unroll
    for (int i = 0; i < 4; i++) {
      const int mrow = m0 + wr*64 + i*16 + g*4;
      const int b = mrow >> 11, s = mrow & 2047;
      #pragma unroll
      for (int j = 0; j < 4; j++) {
        const int n = n0 + wc*64 + j*16 + qr;
        const float bz = bias[n];
        const size_t base = ((size_t)(b*16 + (n >> 6))*2048 + s)*64 + (n & 63);
        #pragma unroll
        for (int r = 0; r < 4; r++) O[base + (size_t)r*64] = f2bf(acc[i][j][r] + bz);
      }
    }
  }
}

// ---------------- flash attention v3: split-KV within 8-wave block ----------------
// Wave (half, wq): half picks t-range [half*1024, half*1024+1024), wq picks 32 q-rows.
// No online max (|scores| <= ~3); partials are pure sums -> combine at end via LDS:
// out = (O0 + O1) / (l0 + l1). 1024 blocks x 8 waves = 32 waves/CU (vs 16 before).
// XCD swizzle: each XCD owns 8 consecutive bh -> K/V working set fits its 4MB L2.
__global__ __launch_bounds__(512, 8) void attn_kernel(
    const u16* __restrict__ Q, const u16* __restrict__ K,
    const u16* __restrict__ Vt, u16* __restrict__ cat)
{
  __shared__ __align__(16) char smem[37376];
  // P region: 8 waves x 2 qsets x [16 q][40] bf16 = 20480B (dead after main loop)
  // Ocomb:    [4 wq][32 q][72] f32 = 36864B (overlays P, used after sync)
  // lpart:    [4 wq][32 q] f32 at offset 36864
  const int tid = threadIdx.x;
  const int lane = tid & 63, w = tid >> 6;
  const int half = w >> 2, wq = w & 3;
  const int bid = blockIdx.x;
  const int logical = (bid & 7) * 128 + (bid >> 3);  // XCD-aware remap (1024 % 8 == 0)
  const int bh = logical >> 4;                       // b*16 + h
  const int xq = logical & 15;
  const int b = bh >> 4, h = bh & 15;
  const int q0 = xq * 128 + wq * 32;
  const int qr = lane & 15, g = lane >> 4;
  u16* P0 = (u16*)smem + (w*2 + 0)*640;
  u16* P1 = (u16*)smem + (w*2 + 1)*640;
  float* Ocomb = (float*)smem;
  float* lpart = (float*)(smem + 36864);

  const u16* Qb = Q  + (size_t)bh * 131072;   // [s][dk]
  const u16* Kb = K  + (size_t)bh * 131072;   // [t][dk]
  const u16* Vb = Vt + (size_t)bh * 131072;   // [dk][s]

  const short8 qa0 = *(const short8*)&Qb[(size_t)(q0 + qr)*64 + g*8];
  const short8 qb0 = *(const short8*)&Qb[(size_t)(q0 + qr)*64 + 32 + g*8];
  const short8 qa1 = *(const short8*)&Qb[(size_t)(q0 + 16 + qr)*64 + g*8];
  const short8 qb1 = *(const short8*)&Qb[(size_t)(q0 + 16 + qr)*64 + 32 + g*8];

  f32x4 o0[4], o1[4];
  #pragma unroll
  for (int d = 0; d < 4; d++) { o0[d] = (f32x4){0.f,0.f,0.f,0.f}; o1[d] = (f32x4){0.f,0.f,0.f,0.f}; }
  float ps0 = 0.f, ps1 = 0.f;
  const float cexp = 0.125f * 1.44269504089f; // 1/sqrt(DK) folded into exp2

  const int tbase = half * 1024;
  for (int tt = 0; tt < 1024; tt += 32) {
    const u16* Kt = &Kb[(size_t)(tbase + tt) * 64];
    short8 k0a = *(const short8*)&Kt[qr*64 + g*8];
    short8 k0b = *(const short8*)&Kt[qr*64 + 32 + g*8];
    short8 k1a = *(const short8*)&Kt[(16 + qr)*64 + g*8];
    short8 k1b = *(const short8*)&Kt[(16 + qr)*64 + 32 + g*8];
    f32x4 s00 = {0.f,0.f,0.f,0.f}, s01 = {0.f,0.f,0.f,0.f};
    f32x4 s10 = {0.f,0.f,0.f,0.f}, s11 = {0.f,0.f,0.f,0.f};
    s00 = __builtin_amdgcn_mfma_f32_16x16x32_bf16(k0a, qa0, s00, 0, 0, 0);
    s00 = __builtin_amdgcn_mfma_f32_16x16x32_bf16(k0b, qb0, s00, 0, 0, 0);
    s01 = __builtin_amdgcn_mfma_f32_16x16x32_bf16(k1a, qa0, s01, 0, 0, 0);
    s01 = __builtin_amdgcn_mfma_f32_16x16x32_bf16(k1b, qb0, s01, 0, 0, 0);
    s10 = __builtin_amdgcn_mfma_f32_16x16x32_bf16(k0a, qa1, s10, 0, 0, 0);
    s10 = __builtin_amdgcn_mfma_f32_16x16x32_bf16(k0b, qb1, s10, 0, 0, 0);
    s11 = __builtin_amdgcn_mfma_f32_16x16x32_bf16(k1a, qa1, s11, 0, 0, 0);
    s11 = __builtin_amdgcn_mfma_f32_16x16x32_bf16(k1b, qb1, s11, 0, 0, 0);
    // exp (no max subtraction), accumulate per-lane partial sums
    u16x4 lo0, hi0, lo1, hi1;
    #pragma unroll
    for (int r = 0; r < 4; r++) {
      float e;
      e = __builtin_amdgcn_exp2f(s00[r]*cexp); ps0 += e; lo0[r] = f2bf(e);
      e = __builtin_amdgcn_exp2f(s01[r]*cexp); ps0 += e; hi0[r] = f2bf(e);
      e = __builtin_amdgcn_exp2f(s10[r]*cexp); ps1 += e; lo1[r] = f2bf(e);
      e = __builtin_amdgcn_exp2f(s11[r]*cexp); ps1 += e; hi1[r] = f2bf(e);
    }
    // P^T redistribute via LDS: write [q][t] rows (stride 40 bf16 = 80B)
    *(u16x4*)&P0[qr*40 + g*4]      = lo0;   // t = 4g..4g+3
    *(u16x4*)&P0[qr*40 + 16 + g*4] = hi0;   // t = 16+4g..16+4g+3
    *(u16x4*)&P1[qr*40 + g*4]      = lo1;
    *(u16x4*)&P1[qr*40 + 16 + g*4] = hi1;
    short8 bp0 = *(const short8*)&P0[qr*40 + g*8];  // t = 8g..8g+7, q = qr
    short8 bp1 = *(const short8*)&P1[qr*40 + g*8];
    // PV: heads^T[dk][q] += V^T[dk][t] . P^T[t][q], 4 dk-tiles of 16
    #pragma unroll
    for (int d = 0; d < 4; d++) {
      short8 av = *(const short8*)&Vb[((size_t)(d*16 + qr))*2048 + tbase + tt + g*8];
      o0[d] = __builtin_amdgcn_mfma_f32_16x16x32_bf16(av, bp0, o0[d], 0, 0, 0);
      o1[d] = __builtin_amdgcn_mfma_f32_16x16x32_bf16(av, bp1, o1[d], 0, 0, 0);
    }
  }
  float l0 = ps0; l0 += __shfl_xor(l0, 16); l0 += __shfl_xor(l0, 32);
  float l1 = ps1; l1 += __shfl_xor(l1, 16); l1 += __shfl_xor(l1, 32);

  __syncthreads();                 // all loops done; P region dead
  if (half == 0) {
    #pragma unroll
    for (int d = 0; d < 4; d++) {
      *(f32x4*)&Ocomb[(wq*32 + qr)*72 + d*16 + g*4]      = o0[d];
      *(f32x4*)&Ocomb[(wq*32 + 16 + qr)*72 + d*16 + g*4] = o1[d];
    }
    if (g == 0) { lpart[wq*32 + qr] = l0; lpart[wq*32 + 16 + qr] = l1; }
  }
  __syncthreads();
  if (half == 1) {
    const float inv0 = 1.0f / (l0 + lpart[wq*32 + qr]);
    const float inv1 = 1.0f / (l1 + lpart[wq*32 + 16 + qr]);
    const size_t base0 = ((size_t)(b*2048 + q0 + qr))*1024 + h*64;
    const size_t base1 = ((size_t)(b*2048 + q0 + 16 + qr))*1024 + h*64;
    #pragma unroll
    for (int d = 0; d < 4; d++) {
      f32x4 a0 = *(const f32x4*)&Ocomb[(wq*32 + qr)*72 + d*16 + g*4];
      f32x4 a1 = *(const f32x4*)&Ocomb[(wq*32 + 16 + qr)*72 + d*16 + g*4];
      u16x4 v0, v1;
      #pragma unroll
      for (int r = 0; r < 4; r++) {
        v0[r] = f2bf((a0[r] + o0[d][r]) * inv0);
        v1[r] = f2bf((a1[r] + o1[d][r]) * inv1);
      }
      *(u16x4*)&cat[base0 + d*16 + g*4] = v0;
      *(u16x4*)&cat[base1 + d*16 + g*4] = v1;
    }
  }
}

// ---------------- output projection: f32 out + bias ----------------
__global__ __launch_bounds__(256) void out_gemm_kernel(
    const u16* __restrict__ A, const u16* __restrict__ Bt,
    const float* __restrict__ bias, float* __restrict__ out)
{
  __shared__ __align__(128) u16 As[4096];
  __shared__ __align__(128) u16 Bs[4096];
  const int lane = threadIdx.x & 63, wid = threadIdx.x >> 6;
  const int wr = wid >> 1, wc = wid & 1;
  const int qr = lane & 15, g = lane >> 4;
  const int m0 = blockIdx.y * 128, n0 = blockIdx.x * 128;

  f32x4 acc[4][4];
  gemm_mainloop(A, Bt, m0, n0, As, Bs, acc);

  #pragma unroll
  for (int i = 0; i < 4; i++) {
    const int mrow = m0 + wr*64 + i*16 + g*4;
    #pragma unroll
    for (int j = 0; j < 4; j++) {
      const int n = n0 + wc*64 + j*16 + qr;
      const float bz = bias[n];
      #pragma unroll
      for (int r = 0; r < 4; r++) out[(size_t)(mrow + r)*1024 + n] = acc[i][j][r] + bz;
    }
  }
}

extern "C" void kernel_launch(void* const* d_in, const int* in_sizes, int n_in,
                              void* d_out, int out_size, void* d_ws, size_t ws_size,
                              hipStream_t stream) {
  const float* x  = (const float*)d_in[0];
  const float* Wq = (const float*)d_in[1];
  const float* bq = (const float*)d_in[2];
  const float* Wk = (const float*)d_in[3];
  const float* bk = (const float*)d_in[4];
  const float* Wv = (const float*)d_in[5];
  const float* bv = (const float*)d_in[6];
  const float* Wo = (const float*)d_in[7];
  const float* bo = (const float*)d_in[8];
  float* out = (float*)d_out;
  char* ws = (char*)d_ws;

  // workspace layout (bytes): xb 16M (reused as cat) | Wt 6M | Wot 2M | Q 16M | K 16M | Vt 16M
  u16* xb  = (u16*)(ws);
  u16* Wt  = (u16*)(ws + 16777216);
  u16* Wot = (u16*)(ws + 23068672);
  u16* Qb  = (u16*)(ws + 25165824);
  u16* Kb  = (u16*)(ws + 41943040);
  u16* Vt  = (u16*)(ws + 58720256);
  u16* cat = xb;  // xb dead after qkv_gemm; attn writes cat there

  cvt_kernel<<<8192, 256, 0, stream>>>(x, Wq, Wk, Wv, Wo, xb, Wt, Wot);
  qkv_gemm_kernel<<<dim3(8, 64, 3), 256, 0, stream>>>(xb, Wt, bq, bk, bv, Qb, Kb, Vt);
  attn_kernel<<<1024, 512, 0, stream>>>(Qb, Kb, Vt, cat);
  out_gemm_kernel<<<dim3(8, 64), 256, 0, stream>>>(cat, Wot, bo, out);
}

// Round 4
// 460.265 us; speedup vs baseline: 1.2967x; 1.2967x over previous
//
#include <hip/hip_runtime.h>
#include <hip/hip_bf16.h>
#include <stdint.h>

typedef unsigned short u16;
typedef __attribute__((ext_vector_type(8))) short short8;   // 8 bf16 (4 VGPRs) MFMA A/B frag
typedef __attribute__((ext_vector_type(4))) float f32x4;    // MFMA C/D frag
typedef __attribute__((ext_vector_type(4))) unsigned short u16x4;

#define DEV static __device__ __forceinline__

// B=4, S=2048, D=1024, H=16, DK=64, DOUT=1024; M = B*S = 8192

DEV u16 f2bf(float f) {  // f32 -> bf16 RNE (compiler emits v_cvt_pk_bf16_f32 for pairs)
  __hip_bfloat16 b = __float2bfloat16(f);
  return *(u16*)&b;
}

DEV void stage16(const u16* g, u16* l) {
  // async global->LDS, 16B per lane; LDS dest = wave-uniform base + lane*16
  __builtin_amdgcn_global_load_lds((const __attribute__((address_space(1))) void*)g,
                                   (__attribute__((address_space(3))) void*)l, 16, 0, 0);
}

// ---------------- conversions / transposes (one launch) ----------------
__global__ __launch_bounds__(256) void cvt_kernel(
    const float* __restrict__ x, const float* __restrict__ Wq,
    const float* __restrict__ Wk, const float* __restrict__ Wv,
    const float* __restrict__ Wo,
    u16* __restrict__ xb, u16* __restrict__ Wt, u16* __restrict__ Wot)
{
  int idx = blockIdx.x * 256 + threadIdx.x;
  if (idx < 1048576) {                      // x: [8192][1024] f32 -> bf16, 8 elems/thread
    int i = idx * 8;
    f32x4 v0 = *(const f32x4*)&x[i];
    f32x4 v1 = *(const f32x4*)&x[i + 4];
    short8 o;
    o[0]=f2bf(v0[0]); o[1]=f2bf(v0[1]); o[2]=f2bf(v0[2]); o[3]=f2bf(v0[3]);
    o[4]=f2bf(v1[0]); o[5]=f2bf(v1[1]); o[6]=f2bf(v1[2]); o[7]=f2bf(v1[3]);
    *(short8*)&xb[i] = o;
  } else if (idx < 1835008) {               // Wq/Wk/Wv [H][D][DK] -> Wt[w][n=h*64+k][d]
    int t = (idx - 1048576) * 4;
    int w = t >> 20; int r = t & 1048575; int n = r >> 10; int d0 = r & 1023;
    const float* W = (w == 0) ? Wq : (w == 1) ? Wk : Wv;
    int h = n >> 6, k = n & 63;
    u16x4 o;
    #pragma unroll
    for (int u = 0; u < 4; u++) o[u] = f2bf(W[(size_t)(h*1024 + d0 + u)*64 + k]);
    *(u16x4*)&Wt[t] = o;
  } else if (idx < 2097152) {               // Wo [f][n] -> Wot[n][f]
    int t = (idx - 1835008) * 4;
    int n = t >> 10, d0 = t & 1023;
    u16x4 o;
    #pragma unroll
    for (int u = 0; u < 4; u++) o[u] = f2bf(Wo[(size_t)(d0 + u)*1024 + n]);
    *(u16x4*)&Wot[t] = o;
  }
}

// ---------------- shared GEMM main loop (128x128 tile, BK=32, 4 waves) ----------------
DEV void gemm_mainloop(const u16* __restrict__ A, const u16* __restrict__ Bt,
                       int m0, int n0, u16* As, u16* Bs, f32x4 acc[4][4])
{
  const int tid = threadIdx.x;
  const int lane = tid & 63, wid = tid >> 6;
  const int wr = wid >> 1, wc = wid & 1;
  const int qr = lane & 15, g = lane >> 4;
  const int c0 = wid * 2, rA = lane >> 2, cA = (lane & 3) * 8;

  #pragma unroll
  for (int i = 0; i < 4; i++)
    #pragma unroll
    for (int j = 0; j < 4; j++) acc[i][j] = (f32x4){0.f, 0.f, 0.f, 0.f};

  for (int kt = 0; kt < 1024; kt += 32) {
    #pragma unroll
    for (int q = 0; q < 2; q++) {
      const int c = c0 + q;                 // chunk of 16 rows (1KB LDS)
      stage16(A  + (size_t)(m0 + c*16 + rA)*1024 + kt + cA, &As[c*512]);
      stage16(Bt + (size_t)(n0 + c*16 + rA)*1024 + kt + cA, &Bs[c*512]);
    }
    __syncthreads();
    short8 af[4], bfr[4];
    #pragma unroll
    for (int i = 0; i < 4; i++) af[i]  = *(const short8*)&As[(wr*64 + i*16 + qr)*32 + g*8];
    #pragma unroll
    for (int j = 0; j < 4; j++) bfr[j] = *(const short8*)&Bs[(wc*64 + j*16 + qr)*32 + g*8];
    #pragma unroll
    for (int i = 0; i < 4; i++)
      #pragma unroll
      for (int j = 0; j < 4; j++)
        acc[i][j] = __builtin_amdgcn_mfma_f32_16x16x32_bf16(af[i], bfr[j], acc[i][j], 0, 0, 0);
    __syncthreads();
  }
}

// ---------------- QKV projection: z picks Q/K/V ----------------
__global__ __launch_bounds__(256) void qkv_gemm_kernel(
    const u16* __restrict__ A, const u16* __restrict__ WtAll,
    const float* __restrict__ bq, const float* __restrict__ bk, const float* __restrict__ bv,
    u16* __restrict__ Qo, u16* __restrict__ Ko, u16* __restrict__ Vo)
{
  __shared__ __align__(128) u16 As[4096];
  __shared__ __align__(128) u16 Bs[4096];
  const int lane = threadIdx.x & 63, wid = threadIdx.x >> 6;
  const int wr = wid >> 1, wc = wid & 1;
  const int qr = lane & 15, g = lane >> 4;
  const int m0 = blockIdx.y * 128, n0 = blockIdx.x * 128;
  const int mode = blockIdx.z;
  const u16* Bt = WtAll + (size_t)mode * 1048576;
  const float* bias = (mode == 0) ? bq : (mode == 1) ? bk : bv;

  f32x4 acc[4][4];
  gemm_mainloop(A, Bt, m0, n0, As, Bs, acc);

  if (mode == 2) {
    // V transposed: Vt[b][h][dk][s], 4 consecutive s per lane -> 8B store
    #pragma unroll
    for (int i = 0; i < 4; i++) {
      const int mrow = m0 + wr*64 + i*16 + g*4;
      const int b = mrow >> 11, s = mrow & 2047;
      #pragma unroll
      for (int j = 0; j < 4; j++) {
        const int n = n0 + wc*64 + j*16 + qr;
        const float bz = bias[n];
        u16x4 v;
        #pragma unroll
        for (int r = 0; r < 4; r++) v[r] = f2bf(acc[i][j][r] + bz);
        *(u16x4*)&Vo[((size_t)(b*16 + (n >> 6))*64 + (n & 63))*2048 + s] = v;
      }
    }
  } else {
    u16* O = (mode == 0) ? Qo : Ko;         // [b][h][s][dk]
    #pragma unroll
    for (int i = 0; i < 4; i++) {
      const int mrow = m0 + wr*64 + i*16 + g*4;
      const int b = mrow >> 11, s = mrow & 2047;
      #pragma unroll
      for (int j = 0; j < 4; j++) {
        const int n = n0 + wc*64 + j*16 + qr;
        const float bz = bias[n];
        const size_t base = ((size_t)(b*16 + (n >> 6))*2048 + s)*64 + (n & 63);
        #pragma unroll
        for (int r = 0; r < 4; r++) O[base + (size_t)r*64] = f2bf(acc[i][j][r] + bz);
      }
    }
  }
}

// ---------------- flash attention v3b: split-KV within 8-wave block ----------------
// Wave (half, wq): half picks t-range [half*1024, half*1024+1024), wq picks 32 q-rows.
// No online max (|scores| <= ~3); partials are pure sums -> combine at end via LDS:
// out = (O0 + O1) / (l0 + l1). 1024 blocks x 8 waves.
// launch_bounds min-waves = 6 (NOT 8): 8 forced VGPR->32 and spilled ~1.1GB to
// scratch (r3: WRITE_SIZE 790MB). Cap 512/6=85 VGPR >= the ~65 the body needs.
__global__ __launch_bounds__(512, 6) void attn_kernel(
    const u16* __restrict__ Q, const u16* __restrict__ K,
    const u16* __restrict__ Vt, u16* __restrict__ cat)
{
  __shared__ __align__(16) char smem[37376];
  // P region: 8 waves x 2 qsets x [16 q][40] bf16 = 20480B (dead after main loop)
  // Ocomb:    [4 wq][32 q][72] f32 = 36864B (overlays P, used after sync)
  // lpart:    [4 wq][32 q] f32 at offset 36864
  const int tid = threadIdx.x;
  const int lane = tid & 63, w = tid >> 6;
  const int half = w >> 2, wq = w & 3;
  const int bid = blockIdx.x;
  const int logical = (bid & 7) * 128 + (bid >> 3);  // XCD-aware remap (1024 % 8 == 0)
  const int bh = logical >> 4;                       // b*16 + h
  const int xq = logical & 15;
  const int b = bh >> 4, h = bh & 15;
  const int q0 = xq * 128 + wq * 32;
  const int qr = lane & 15, g = lane >> 4;
  u16* P0 = (u16*)smem + (w*2 + 0)*640;
  u16* P1 = (u16*)smem + (w*2 + 1)*640;
  float* Ocomb = (float*)smem;
  float* lpart = (float*)(smem + 36864);

  const u16* Qb = Q  + (size_t)bh * 131072;   // [s][dk]
  const u16* Kb = K  + (size_t)bh * 131072;   // [t][dk]
  const u16* Vb = Vt + (size_t)bh * 131072;   // [dk][s]

  const short8 qa0 = *(const short8*)&Qb[(size_t)(q0 + qr)*64 + g*8];
  const short8 qb0 = *(const short8*)&Qb[(size_t)(q0 + qr)*64 + 32 + g*8];
  const short8 qa1 = *(const short8*)&Qb[(size_t)(q0 + 16 + qr)*64 + g*8];
  const short8 qb1 = *(const short8*)&Qb[(size_t)(q0 + 16 + qr)*64 + 32 + g*8];

  f32x4 o0[4], o1[4];
  #pragma unroll
  for (int d = 0; d < 4; d++) { o0[d] = (f32x4){0.f,0.f,0.f,0.f}; o1[d] = (f32x4){0.f,0.f,0.f,0.f}; }
  float ps0 = 0.f, ps1 = 0.f;
  const float cexp = 0.125f * 1.44269504089f; // 1/sqrt(DK) folded into exp2

  const int tbase = half * 1024;
  for (int tt = 0; tt < 1024; tt += 32) {
    const u16* Kt = &Kb[(size_t)(tbase + tt) * 64];
    short8 k0a = *(const short8*)&Kt[qr*64 + g*8];
    short8 k0b = *(const short8*)&Kt[qr*64 + 32 + g*8];
    short8 k1a = *(const short8*)&Kt[(16 + qr)*64 + g*8];
    short8 k1b = *(const short8*)&Kt[(16 + qr)*64 + 32 + g*8];
    f32x4 s00 = {0.f,0.f,0.f,0.f}, s01 = {0.f,0.f,0.f,0.f};
    f32x4 s10 = {0.f,0.f,0.f,0.f}, s11 = {0.f,0.f,0.f,0.f};
    s00 = __builtin_amdgcn_mfma_f32_16x16x32_bf16(k0a, qa0, s00, 0, 0, 0);
    s00 = __builtin_amdgcn_mfma_f32_16x16x32_bf16(k0b, qb0, s00, 0, 0, 0);
    s01 = __builtin_amdgcn_mfma_f32_16x16x32_bf16(k1a, qa0, s01, 0, 0, 0);
    s01 = __builtin_amdgcn_mfma_f32_16x16x32_bf16(k1b, qb0, s01, 0, 0, 0);
    s10 = __builtin_amdgcn_mfma_f32_16x16x32_bf16(k0a, qa1, s10, 0, 0, 0);
    s10 = __builtin_amdgcn_mfma_f32_16x16x32_bf16(k0b, qb1, s10, 0, 0, 0);
    s11 = __builtin_amdgcn_mfma_f32_16x16x32_bf16(k1a, qa1, s11, 0, 0, 0);
    s11 = __builtin_amdgcn_mfma_f32_16x16x32_bf16(k1b, qb1, s11, 0, 0, 0);
    // exp (no max subtraction), accumulate per-lane partial sums
    u16x4 lo0, hi0, lo1, hi1;
    #pragma unroll
    for (int r = 0; r < 4; r++) {
      float e;
      e = __builtin_amdgcn_exp2f(s00[r]*cexp); ps0 += e; lo0[r] = f2bf(e);
      e = __builtin_amdgcn_exp2f(s01[r]*cexp); ps0 += e; hi0[r] = f2bf(e);
      e = __builtin_amdgcn_exp2f(s10[r]*cexp); ps1 += e; lo1[r] = f2bf(e);
      e = __builtin_amdgcn_exp2f(s11[r]*cexp); ps1 += e; hi1[r] = f2bf(e);
    }
    // P^T redistribute via LDS: write [q][t] rows (stride 40 bf16 = 80B)
    *(u16x4*)&P0[qr*40 + g*4]      = lo0;   // t = 4g..4g+3
    *(u16x4*)&P0[qr*40 + 16 + g*4] = hi0;   // t = 16+4g..16+4g+3
    *(u16x4*)&P1[qr*40 + g*4]      = lo1;
    *(u16x4*)&P1[qr*40 + 16 + g*4] = hi1;
    short8 bp0 = *(const short8*)&P0[qr*40 + g*8];  // t = 8g..8g+7, q = qr
    short8 bp1 = *(const short8*)&P1[qr*40 + g*8];
    // PV: heads^T[dk][q] += V^T[dk][t] . P^T[t][q], 4 dk-tiles of 16
    #pragma unroll
    for (int d = 0; d < 4; d++) {
      short8 av = *(const short8*)&Vb[((size_t)(d*16 + qr))*2048 + tbase + tt + g*8];
      o0[d] = __builtin_amdgcn_mfma_f32_16x16x32_bf16(av, bp0, o0[d], 0, 0, 0);
      o1[d] = __builtin_amdgcn_mfma_f32_16x16x32_bf16(av, bp1, o1[d], 0, 0, 0);
    }
  }
  float l0 = ps0; l0 += __shfl_xor(l0, 16); l0 += __shfl_xor(l0, 32);
  float l1 = ps1; l1 += __shfl_xor(l1, 16); l1 += __shfl_xor(l1, 32);

  __syncthreads();                 // all loops done; P region dead
  if (half == 0) {
    #pragma unroll
    for (int d = 0; d < 4; d++) {
      *(f32x4*)&Ocomb[(wq*32 + qr)*72 + d*16 + g*4]      = o0[d];
      *(f32x4*)&Ocomb[(wq*32 + 16 + qr)*72 + d*16 + g*4] = o1[d];
    }
    if (g == 0) { lpart[wq*32 + qr] = l0; lpart[wq*32 + 16 + qr] = l1; }
  }
  __syncthreads();
  if (half == 1) {
    const float inv0 = 1.0f / (l0 + lpart[wq*32 + qr]);
    const float inv1 = 1.0f / (l1 + lpart[wq*32 + 16 + qr]);
    const size_t base0 = ((size_t)(b*2048 + q0 + qr))*1024 + h*64;
    const size_t base1 = ((size_t)(b*2048 + q0 + 16 + qr))*1024 + h*64;
    #pragma unroll
    for (int d = 0; d < 4; d++) {
      f32x4 a0 = *(const f32x4*)&Ocomb[(wq*32 + qr)*72 + d*16 + g*4];
      f32x4 a1 = *(const f32x4*)&Ocomb[(wq*32 + 16 + qr)*72 + d*16 + g*4];
      u16x4 v0, v1;
      #pragma unroll
      for (int r = 0; r < 4; r++) {
        v0[r] = f2bf((a0[r] + o0[d][r]) * inv0);
        v1[r] = f2bf((a1[r] + o1[d][r]) * inv1);
      }
      *(u16x4*)&cat[base0 + d*16 + g*4] = v0;
      *(u16x4*)&cat[base1 + d*16 + g*4] = v1;
    }
  }
}

// ---------------- output projection: f32 out + bias ----------------
__global__ __launch_bounds__(256) void out_gemm_kernel(
    const u16* __restrict__ A, const u16* __restrict__ Bt,
    const float* __restrict__ bias, float* __restrict__ out)
{
  __shared__ __align__(128) u16 As[4096];
  __shared__ __align__(128) u16 Bs[4096];
  const int lane = threadIdx.x & 63, wid = threadIdx.x >> 6;
  const int wr = wid >> 1, wc = wid & 1;
  const int qr = lane & 15, g = lane >> 4;
  const int m0 = blockIdx.y * 128, n0 = blockIdx.x * 128;

  f32x4 acc[4][4];
  gemm_mainloop(A, Bt, m0, n0, As, Bs, acc);

  #pragma unroll
  for (int i = 0; i < 4; i++) {
    const int mrow = m0 + wr*64 + i*16 + g*4;
    #pragma unroll
    for (int j = 0; j < 4; j++) {
      const int n = n0 + wc*64 + j*16 + qr;
      const float bz = bias[n];
      #pragma unroll
      for (int r = 0; r < 4; r++) out[(size_t)(mrow + r)*1024 + n] = acc[i][j][r] + bz;
    }
  }
}

extern "C" void kernel_launch(void* const* d_in, const int* in_sizes, int n_in,
                              void* d_out, int out_size, void* d_ws, size_t ws_size,
                              hipStream_t stream) {
  const float* x  = (const float*)d_in[0];
  const float* Wq = (const float*)d_in[1];
  const float* bq = (const float*)d_in[2];
  const float* Wk = (const float*)d_in[3];
  const float* bk = (const float*)d_in[4];
  const float* Wv = (const float*)d_in[5];
  const float* bv = (const float*)d_in[6];
  const float* Wo = (const float*)d_in[7];
  const float* bo = (const float*)d_in[8];
  float* out = (float*)d_out;
  char* ws = (char*)d_ws;

  // workspace layout (bytes): xb 16M (reused as cat) | Wt 6M | Wot 2M | Q 16M | K 16M | Vt 16M
  u16* xb  = (u16*)(ws);
  u16* Wt  = (u16*)(ws + 16777216);
  u16* Wot = (u16*)(ws + 23068672);
  u16* Qb  = (u16*)(ws + 25165824);
  u16* Kb  = (u16*)(ws + 41943040);
  u16* Vt  = (u16*)(ws + 58720256);
  u16* cat = xb;  // xb dead after qkv_gemm; attn writes cat there

  cvt_kernel<<<8192, 256, 0, stream>>>(x, Wq, Wk, Wv, Wo, xb, Wt, Wot);
  qkv_gemm_kernel<<<dim3(8, 64, 3), 256, 0, stream>>>(xb, Wt, bq, bk, bv, Qb, Kb, Vt);
  attn_kernel<<<1024, 512, 0, stream>>>(Qb, Kb, Vt, cat);
  out_gemm_kernel<<<dim3(8, 64), 256, 0, stream>>>(cat, Wot, bo, out);
}

// Round 5
// 372.376 us; speedup vs baseline: 1.6028x; 1.2360x over previous
//
#include <hip/hip_runtime.h>
#include <hip/hip_bf16.h>
#include <stdint.h>

typedef unsigned short u16;
typedef __attribute__((ext_vector_type(8))) short short8;   // 8 bf16 (4 VGPRs) MFMA A/B frag
typedef __attribute__((ext_vector_type(4))) float f32x4;    // MFMA C/D frag
typedef __attribute__((ext_vector_type(4))) unsigned short u16x4;

#define DEV static __device__ __forceinline__

// B=4, S=2048, D=1024, H=16, DK=64, DOUT=1024; M = B*S = 8192

DEV u16 f2bf(float f) {  // f32 -> bf16 RNE (compiler emits v_cvt_pk_bf16_f32 for pairs)
  __hip_bfloat16 b = __float2bfloat16(f);
  return *(u16*)&b;
}

DEV void stage16(const u16* g, u16* l) {
  // async global->LDS, 16B per lane; LDS dest = wave-uniform base + lane*16
  __builtin_amdgcn_global_load_lds((const __attribute__((address_space(1))) void*)g,
                                   (__attribute__((address_space(3))) void*)l, 16, 0, 0);
}

// ---------------- conversions / transposes (one launch) ----------------
__global__ __launch_bounds__(256) void cvt_kernel(
    const float* __restrict__ x, const float* __restrict__ Wq,
    const float* __restrict__ Wk, const float* __restrict__ Wv,
    const float* __restrict__ Wo,
    u16* __restrict__ xb, u16* __restrict__ Wt, u16* __restrict__ Wot)
{
  int idx = blockIdx.x * 256 + threadIdx.x;
  if (idx < 1048576) {                      // x: [8192][1024] f32 -> bf16, 8 elems/thread
    int i = idx * 8;
    f32x4 v0 = *(const f32x4*)&x[i];
    f32x4 v1 = *(const f32x4*)&x[i + 4];
    short8 o;
    o[0]=f2bf(v0[0]); o[1]=f2bf(v0[1]); o[2]=f2bf(v0[2]); o[3]=f2bf(v0[3]);
    o[4]=f2bf(v1[0]); o[5]=f2bf(v1[1]); o[6]=f2bf(v1[2]); o[7]=f2bf(v1[3]);
    *(short8*)&xb[i] = o;
  } else if (idx < 1835008) {               // Wq/Wk/Wv [H][D][DK] -> Wt[w][n=h*64+k][d]
    int t = (idx - 1048576) * 4;
    int w = t >> 20; int r = t & 1048575; int n = r >> 10; int d0 = r & 1023;
    const float* W = (w == 0) ? Wq : (w == 1) ? Wk : Wv;
    int h = n >> 6, k = n & 63;
    u16x4 o;
    #pragma unroll
    for (int u = 0; u < 4; u++) o[u] = f2bf(W[(size_t)(h*1024 + d0 + u)*64 + k]);
    *(u16x4*)&Wt[t] = o;
  } else if (idx < 2097152) {               // Wo [f][n] -> Wot[n][f]
    int t = (idx - 1835008) * 4;
    int n = t >> 10, d0 = t & 1023;
    u16x4 o;
    #pragma unroll
    for (int u = 0; u < 4; u++) o[u] = f2bf(Wo[(size_t)(d0 + u)*1024 + n]);
    *(u16x4*)&Wot[t] = o;
  }
}

// ---------------- shared GEMM main loop (128x128 tile, BK=32, 4 waves) ----------------
DEV void gemm_mainloop(const u16* __restrict__ A, const u16* __restrict__ Bt,
                       int m0, int n0, u16* As, u16* Bs, f32x4 acc[4][4])
{
  const int tid = threadIdx.x;
  const int lane = tid & 63, wid = tid >> 6;
  const int wr = wid >> 1, wc = wid & 1;
  const int qr = lane & 15, g = lane >> 4;
  const int c0 = wid * 2, rA = lane >> 2, cA = (lane & 3) * 8;

  #pragma unroll
  for (int i = 0; i < 4; i++)
    #pragma unroll
    for (int j = 0; j < 4; j++) acc[i][j] = (f32x4){0.f, 0.f, 0.f, 0.f};

  for (int kt = 0; kt < 1024; kt += 32) {
    #pragma unroll
    for (int q = 0; q < 2; q++) {
      const int c = c0 + q;                 // chunk of 16 rows (1KB LDS)
      stage16(A  + (size_t)(m0 + c*16 + rA)*1024 + kt + cA, &As[c*512]);
      stage16(Bt + (size_t)(n0 + c*16 + rA)*1024 + kt + cA, &Bs[c*512]);
    }
    __syncthreads();
    short8 af[4], bfr[4];
    #pragma unroll
    for (int i = 0; i < 4; i++) af[i]  = *(const short8*)&As[(wr*64 + i*16 + qr)*32 + g*8];
    #pragma unroll
    for (int j = 0; j < 4; j++) bfr[j] = *(const short8*)&Bs[(wc*64 + j*16 + qr)*32 + g*8];
    #pragma unroll
    for (int i = 0; i < 4; i++)
      #pragma unroll
      for (int j = 0; j < 4; j++)
        acc[i][j] = __builtin_amdgcn_mfma_f32_16x16x32_bf16(af[i], bfr[j], acc[i][j], 0, 0, 0);
    __syncthreads();
  }
}

// ---------------- QKV projection: z picks Q/K/V ----------------
__global__ __launch_bounds__(256) void qkv_gemm_kernel(
    const u16* __restrict__ A, const u16* __restrict__ WtAll,
    const float* __restrict__ bq, const float* __restrict__ bk, const float* __restrict__ bv,
    u16* __restrict__ Qo, u16* __restrict__ Ko, u16* __restrict__ Vo)
{
  __shared__ __align__(128) u16 As[4096];
  __shared__ __align__(128) u16 Bs[4096];
  const int lane = threadIdx.x & 63, wid = threadIdx.x >> 6;
  const int wr = wid >> 1, wc = wid & 1;
  const int qr = lane & 15, g = lane >> 4;
  const int m0 = blockIdx.y * 128, n0 = blockIdx.x * 128;
  const int mode = blockIdx.z;
  const u16* Bt = WtAll + (size_t)mode * 1048576;
  const float* bias = (mode == 0) ? bq : (mode == 1) ? bk : bv;

  f32x4 acc[4][4];
  gemm_mainloop(A, Bt, m0, n0, As, Bs, acc);

  if (mode == 2) {
    // V transposed: Vt[b][h][dk][s], 4 consecutive s per lane -> 8B store
    #pragma unroll
    for (int i = 0; i < 4; i++) {
      const int mrow = m0 + wr*64 + i*16 + g*4;
      const int b = mrow >> 11, s = mrow & 2047;
      #pragma unroll
      for (int j = 0; j < 4; j++) {
        const int n = n0 + wc*64 + j*16 + qr;
        const float bz = bias[n];
        u16x4 v;
        #pragma unroll
        for (int r = 0; r < 4; r++) v[r] = f2bf(acc[i][j][r] + bz);
        *(u16x4*)&Vo[((size_t)(b*16 + (n >> 6))*64 + (n & 63))*2048 + s] = v;
      }
    }
  } else {
    u16* O = (mode == 0) ? Qo : Ko;         // [b][h][s][dk]
    #pragma unroll
    for (int i = 0; i < 4; i++) {
      const int mrow = m0 + wr*64 + i*16 + g*4;
      const int b = mrow >> 11, s = mrow & 2047;
      #pragma unroll
      for (int j = 0; j < 4; j++) {
        const int n = n0 + wc*64 + j*16 + qr;
        const float bz = bias[n];
        const size_t base = ((size_t)(b*16 + (n >> 6))*2048 + s)*64 + (n & 63);
        #pragma unroll
        for (int r = 0; r < 4; r++) O[base + (size_t)r*64] = f2bf(acc[i][j][r] + bz);
      }
    }
  }
}

// ---------------- flash attention v4: r2 structure + ILP ----------------
// 4 independent waves/block, 32 q-rows each, full 2048-t sweep (no combine).
// NEW vs r2: (a) XCD-aware block swizzle (validated r4: FETCH 139->39MB);
// (b) K-fragment rotation one tile ahead + V loads issued at iter top ->
// L2 latency hidden under compute; (c) launch_bounds(256,4): 128-VGPR cap
// is free (grid limits to 4 waves/SIMD) and avoids r3/r4 spill disasters;
// (d) s_setprio(1) around MFMA clusters (independent-wave attn: +4-7%, m191).
__global__ __launch_bounds__(256, 4) void attn_kernel(
    const u16* __restrict__ Q, const u16* __restrict__ K,
    const u16* __restrict__ Vt, u16* __restrict__ cat)
{
  __shared__ __align__(16) u16 Pl[5120];      // 4 waves x 2 q-sets x [16 q][40] bf16
  const int lane = threadIdx.x & 63, w = threadIdx.x >> 6;
  const int bid = blockIdx.x;
  const int logical = (bid & 7) * 128 + (bid >> 3);  // XCD swizzle (1024 % 8 == 0)
  const int bh = logical >> 4;                 // b*16 + h
  const int xq = logical & 15;
  const int b = bh >> 4, h = bh & 15;
  const int q0 = xq * 128 + w * 32;            // 32 q-rows per wave
  const int qr = lane & 15, g = lane >> 4;
  u16* P0 = &Pl[(w*2 + 0)*640];
  u16* P1 = &Pl[(w*2 + 1)*640];

  const u16* Qb = Q  + (size_t)bh * 131072;   // [s][dk]
  const u16* Kb = K  + (size_t)bh * 131072;   // [t][dk]
  const u16* Vb = Vt + (size_t)bh * 131072;   // [dk][s]

  const short8 qa0 = *(const short8*)&Qb[(size_t)(q0 + qr)*64 + g*8];
  const short8 qb0 = *(const short8*)&Qb[(size_t)(q0 + qr)*64 + 32 + g*8];
  const short8 qa1 = *(const short8*)&Qb[(size_t)(q0 + 16 + qr)*64 + g*8];
  const short8 qb1 = *(const short8*)&Qb[(size_t)(q0 + 16 + qr)*64 + 32 + g*8];

  f32x4 o0[4], o1[4];
  #pragma unroll
  for (int d = 0; d < 4; d++) { o0[d] = (f32x4){0.f,0.f,0.f,0.f}; o1[d] = (f32x4){0.f,0.f,0.f,0.f}; }
  float ps0 = 0.f, ps1 = 0.f;
  const float cexp = 0.125f * 1.44269504089f; // 1/sqrt(DK) folded into exp2

  // preload K tile 0 fragments
  short8 kc0 = *(const short8*)&Kb[qr*64 + g*8];
  short8 kc1 = *(const short8*)&Kb[qr*64 + 32 + g*8];
  short8 kc2 = *(const short8*)&Kb[(16 + qr)*64 + g*8];
  short8 kc3 = *(const short8*)&Kb[(16 + qr)*64 + 32 + g*8];

  for (int tt = 0; tt < 2048; tt += 32) {
    // issue V loads for CURRENT tile early (consumed after exp+LDS chain)
    short8 vv0 = *(const short8*)&Vb[(size_t)( 0 + qr)*2048 + tt + g*8];
    short8 vv1 = *(const short8*)&Vb[(size_t)(16 + qr)*2048 + tt + g*8];
    short8 vv2 = *(const short8*)&Vb[(size_t)(32 + qr)*2048 + tt + g*8];
    short8 vv3 = *(const short8*)&Vb[(size_t)(48 + qr)*2048 + tt + g*8];
    // issue K loads for NEXT tile (wrap to 0 on last iter: harmless reload)
    const int tn = (tt + 32) & 2047;
    const u16* Kn = &Kb[(size_t)tn * 64];
    short8 kn0 = *(const short8*)&Kn[qr*64 + g*8];
    short8 kn1 = *(const short8*)&Kn[qr*64 + 32 + g*8];
    short8 kn2 = *(const short8*)&Kn[(16 + qr)*64 + g*8];
    short8 kn3 = *(const short8*)&Kn[(16 + qr)*64 + 32 + g*8];

    f32x4 s00 = {0.f,0.f,0.f,0.f}, s01 = {0.f,0.f,0.f,0.f};
    f32x4 s10 = {0.f,0.f,0.f,0.f}, s11 = {0.f,0.f,0.f,0.f};
    __builtin_amdgcn_s_setprio(1);
    s00 = __builtin_amdgcn_mfma_f32_16x16x32_bf16(kc0, qa0, s00, 0, 0, 0);
    s00 = __builtin_amdgcn_mfma_f32_16x16x32_bf16(kc1, qb0, s00, 0, 0, 0);
    s01 = __builtin_amdgcn_mfma_f32_16x16x32_bf16(kc2, qa0, s01, 0, 0, 0);
    s01 = __builtin_amdgcn_mfma_f32_16x16x32_bf16(kc3, qb0, s01, 0, 0, 0);
    s10 = __builtin_amdgcn_mfma_f32_16x16x32_bf16(kc0, qa1, s10, 0, 0, 0);
    s10 = __builtin_amdgcn_mfma_f32_16x16x32_bf16(kc1, qb1, s10, 0, 0, 0);
    s11 = __builtin_amdgcn_mfma_f32_16x16x32_bf16(kc2, qa1, s11, 0, 0, 0);
    s11 = __builtin_amdgcn_mfma_f32_16x16x32_bf16(kc3, qb1, s11, 0, 0, 0);
    __builtin_amdgcn_s_setprio(0);
    // exp (no max subtraction: |scores| <= ~3), per-lane partial sums
    u16x4 lo0, hi0, lo1, hi1;
    #pragma unroll
    for (int r = 0; r < 4; r++) {
      float e;
      e = __builtin_amdgcn_exp2f(s00[r]*cexp); ps0 += e; lo0[r] = f2bf(e);
      e = __builtin_amdgcn_exp2f(s01[r]*cexp); ps0 += e; hi0[r] = f2bf(e);
      e = __builtin_amdgcn_exp2f(s10[r]*cexp); ps1 += e; lo1[r] = f2bf(e);
      e = __builtin_amdgcn_exp2f(s11[r]*cexp); ps1 += e; hi1[r] = f2bf(e);
    }
    // P^T redistribute via per-wave LDS round-trip (stride 40 bf16 = 80B rows)
    *(u16x4*)&P0[qr*40 + g*4]      = lo0;   // t = 4g..4g+3
    *(u16x4*)&P0[qr*40 + 16 + g*4] = hi0;   // t = 16+4g..16+4g+3
    *(u16x4*)&P1[qr*40 + g*4]      = lo1;
    *(u16x4*)&P1[qr*40 + 16 + g*4] = hi1;
    short8 bp0 = *(const short8*)&P0[qr*40 + g*8];  // t = 8g..8g+7, q = qr
    short8 bp1 = *(const short8*)&P1[qr*40 + g*8];
    // PV: heads^T[dk][q] += V^T[dk][t] . P^T[t][q], 4 dk-tiles of 16
    __builtin_amdgcn_s_setprio(1);
    o0[0] = __builtin_amdgcn_mfma_f32_16x16x32_bf16(vv0, bp0, o0[0], 0, 0, 0);
    o1[0] = __builtin_amdgcn_mfma_f32_16x16x32_bf16(vv0, bp1, o1[0], 0, 0, 0);
    o0[1] = __builtin_amdgcn_mfma_f32_16x16x32_bf16(vv1, bp0, o0[1], 0, 0, 0);
    o1[1] = __builtin_amdgcn_mfma_f32_16x16x32_bf16(vv1, bp1, o1[1], 0, 0, 0);
    o0[2] = __builtin_amdgcn_mfma_f32_16x16x32_bf16(vv2, bp0, o0[2], 0, 0, 0);
    o1[2] = __builtin_amdgcn_mfma_f32_16x16x32_bf16(vv2, bp1, o1[2], 0, 0, 0);
    o0[3] = __builtin_amdgcn_mfma_f32_16x16x32_bf16(vv3, bp0, o0[3], 0, 0, 0);
    o1[3] = __builtin_amdgcn_mfma_f32_16x16x32_bf16(vv3, bp1, o1[3], 0, 0, 0);
    __builtin_amdgcn_s_setprio(0);
    // rotate prefetched K
    kc0 = kn0; kc1 = kn1; kc2 = kn2; kc3 = kn3;
  }
  float l0 = ps0; l0 += __shfl_xor(l0, 16); l0 += __shfl_xor(l0, 32);
  float l1 = ps1; l1 += __shfl_xor(l1, 16); l1 += __shfl_xor(l1, 32);
  const float inv0 = 1.0f / l0, inv1 = 1.0f / l1;
  const size_t base0 = ((size_t)(b*2048 + q0 + qr))*1024 + h*64;
  const size_t base1 = ((size_t)(b*2048 + q0 + 16 + qr))*1024 + h*64;
  #pragma unroll
  for (int d = 0; d < 4; d++) {
    u16x4 v0, v1;
    #pragma unroll
    for (int r = 0; r < 4; r++) { v0[r] = f2bf(o0[d][r] * inv0); v1[r] = f2bf(o1[d][r] * inv1); }
    *(u16x4*)&cat[base0 + d*16 + g*4] = v0;
    *(u16x4*)&cat[base1 + d*16 + g*4] = v1;
  }
}

// ---------------- output projection: f32 out + bias ----------------
__global__ __launch_bounds__(256) void out_gemm_kernel(
    const u16* __restrict__ A, const u16* __restrict__ Bt,
    const float* __restrict__ bias, float* __restrict__ out)
{
  __shared__ __align__(128) u16 As[4096];
  __shared__ __align__(128) u16 Bs[4096];
  const int lane = threadIdx.x & 63, wid = threadIdx.x >> 6;
  const int wr = wid >> 1, wc = wid & 1;
  const int qr = lane & 15, g = lane >> 4;
  const int m0 = blockIdx.y * 128, n0 = blockIdx.x * 128;

  f32x4 acc[4][4];
  gemm_mainloop(A, Bt, m0, n0, As, Bs, acc);

  #pragma unroll
  for (int i = 0; i < 4; i++) {
    const int mrow = m0 + wr*64 + i*16 + g*4;
    #pragma unroll
    for (int j = 0; j < 4; j++) {
      const int n = n0 + wc*64 + j*16 + qr;
      const float bz = bias[n];
      #pragma unroll
      for (int r = 0; r < 4; r++) out[(size_t)(mrow + r)*1024 + n] = acc[i][j][r] + bz;
    }
  }
}

extern "C" void kernel_launch(void* const* d_in, const int* in_sizes, int n_in,
                              void* d_out, int out_size, void* d_ws, size_t ws_size,
                              hipStream_t stream) {
  const float* x  = (const float*)d_in[0];
  const float* Wq = (const float*)d_in[1];
  const float* bq = (const float*)d_in[2];
  const float* Wk = (const float*)d_in[3];
  const float* bk = (const float*)d_in[4];
  const float* Wv = (const float*)d_in[5];
  const float* bv = (const float*)d_in[6];
  const float* Wo = (const float*)d_in[7];
  const float* bo = (const float*)d_in[8];
  float* out = (float*)d_out;
  char* ws = (char*)d_ws;

  // workspace layout (bytes): xb 16M (reused as cat) | Wt 6M | Wot 2M | Q 16M | K 16M | Vt 16M
  u16* xb  = (u16*)(ws);
  u16* Wt  = (u16*)(ws + 16777216);
  u16* Wot = (u16*)(ws + 23068672);
  u16* Qb  = (u16*)(ws + 25165824);
  u16* Kb  = (u16*)(ws + 41943040);
  u16* Vt  = (u16*)(ws + 58720256);
  u16* cat = xb;  // xb dead after qkv_gemm; attn writes cat there

  cvt_kernel<<<8192, 256, 0, stream>>>(x, Wq, Wk, Wv, Wo, xb, Wt, Wot);
  qkv_gemm_kernel<<<dim3(8, 64, 3), 256, 0, stream>>>(xb, Wt, bq, bk, bv, Qb, Kb, Vt);
  attn_kernel<<<1024, 256, 0, stream>>>(Qb, Kb, Vt, cat);
  out_gemm_kernel<<<dim3(8, 64), 256, 0, stream>>>(cat, Wot, bo, out);
}

// Round 6
// 233.093 us; speedup vs baseline: 2.5605x; 1.5975x over previous
//
#include <hip/hip_runtime.h>
#include <hip/hip_bf16.h>
#include <stdint.h>

typedef unsigned short u16;
typedef __attribute__((ext_vector_type(8))) short short8;   // 8 bf16 (4 VGPRs) MFMA A/B frag
typedef __attribute__((ext_vector_type(4))) float f32x4;    // MFMA C/D frag
typedef __attribute__((ext_vector_type(4))) unsigned short u16x4;

#define DEV static __device__ __forceinline__

// B=4, S=2048, D=1024, H=16, DK=64, DOUT=1024; M = B*S = 8192

DEV u16 f2bf(float f) {  // f32 -> bf16 RNE (compiler emits v_cvt_pk_bf16_f32 for pairs)
  __hip_bfloat16 b = __float2bfloat16(f);
  return *(u16*)&b;
}

DEV void stage16(const u16* g, u16* l) {
  // async global->LDS, 16B per lane; LDS dest = wave-uniform base + lane*16
  __builtin_amdgcn_global_load_lds((const __attribute__((address_space(1))) void*)g,
                                   (__attribute__((address_space(3))) void*)l, 16, 0, 0);
}

// ---------------- conversions / transposes (one launch) ----------------
__global__ __launch_bounds__(256) void cvt_kernel(
    const float* __restrict__ x, const float* __restrict__ Wq,
    const float* __restrict__ Wk, const float* __restrict__ Wv,
    const float* __restrict__ Wo,
    u16* __restrict__ xb, u16* __restrict__ Wt, u16* __restrict__ Wot)
{
  int idx = blockIdx.x * 256 + threadIdx.x;
  if (idx < 1048576) {                      // x: [8192][1024] f32 -> bf16, 8 elems/thread
    int i = idx * 8;
    f32x4 v0 = *(const f32x4*)&x[i];
    f32x4 v1 = *(const f32x4*)&x[i + 4];
    short8 o;
    o[0]=f2bf(v0[0]); o[1]=f2bf(v0[1]); o[2]=f2bf(v0[2]); o[3]=f2bf(v0[3]);
    o[4]=f2bf(v1[0]); o[5]=f2bf(v1[1]); o[6]=f2bf(v1[2]); o[7]=f2bf(v1[3]);
    *(short8*)&xb[i] = o;
  } else if (idx < 1835008) {               // Wq/Wk/Wv [H][D][DK] -> Wt[w][n=h*64+k][d]
    int t = (idx - 1048576) * 4;
    int w = t >> 20; int r = t & 1048575; int n = r >> 10; int d0 = r & 1023;
    const float* W = (w == 0) ? Wq : (w == 1) ? Wk : Wv;
    int h = n >> 6, k = n & 63;
    u16x4 o;
    #pragma unroll
    for (int u = 0; u < 4; u++) o[u] = f2bf(W[(size_t)(h*1024 + d0 + u)*64 + k]);
    *(u16x4*)&Wt[t] = o;
  } else if (idx < 2097152) {               // Wo [f][n] -> Wot[n][f]
    int t = (idx - 1835008) * 4;
    int n = t >> 10, d0 = t & 1023;
    u16x4 o;
    #pragma unroll
    for (int u = 0; u < 4; u++) o[u] = f2bf(Wo[(size_t)(d0 + u)*1024 + n]);
    *(u16x4*)&Wot[t] = o;
  }
}

// ---------------- shared GEMM main loop (128x128 tile, BK=32, 4 waves) ----------------
DEV void gemm_mainloop(const u16* __restrict__ A, const u16* __restrict__ Bt,
                       int m0, int n0, u16* As, u16* Bs, f32x4 acc[4][4])
{
  const int tid = threadIdx.x;
  const int lane = tid & 63, wid = tid >> 6;
  const int wr = wid >> 1, wc = wid & 1;
  const int qr = lane & 15, g = lane >> 4;
  const int c0 = wid * 2, rA = lane >> 2, cA = (lane & 3) * 8;

  #pragma unroll
  for (int i = 0; i < 4; i++)
    #pragma unroll
    for (int j = 0; j < 4; j++) acc[i][j] = (f32x4){0.f, 0.f, 0.f, 0.f};

  for (int kt = 0; kt < 1024; kt += 32) {
    #pragma unroll
    for (int q = 0; q < 2; q++) {
      const int c = c0 + q;                 // chunk of 16 rows (1KB LDS)
      stage16(A  + (size_t)(m0 + c*16 + rA)*1024 + kt + cA, &As[c*512]);
      stage16(Bt + (size_t)(n0 + c*16 + rA)*1024 + kt + cA, &Bs[c*512]);
    }
    __syncthreads();
    short8 af[4], bfr[4];
    #pragma unroll
    for (int i = 0; i < 4; i++) af[i]  = *(const short8*)&As[(wr*64 + i*16 + qr)*32 + g*8];
    #pragma unroll
    for (int j = 0; j < 4; j++) bfr[j] = *(const short8*)&Bs[(wc*64 + j*16 + qr)*32 + g*8];
    #pragma unroll
    for (int i = 0; i < 4; i++)
      #pragma unroll
      for (int j = 0; j < 4; j++)
        acc[i][j] = __builtin_amdgcn_mfma_f32_16x16x32_bf16(af[i], bfr[j], acc[i][j], 0, 0, 0);
    __syncthreads();
  }
}

// ---------------- QKV projection: z picks Q/K/V ----------------
__global__ __launch_bounds__(256) void qkv_gemm_kernel(
    const u16* __restrict__ A, const u16* __restrict__ WtAll,
    const float* __restrict__ bq, const float* __restrict__ bk, const float* __restrict__ bv,
    u16* __restrict__ Qo, u16* __restrict__ Ko, u16* __restrict__ Vo)
{
  __shared__ __align__(128) u16 As[4096];
  __shared__ __align__(128) u16 Bs[4096];
  const int lane = threadIdx.x & 63, wid = threadIdx.x >> 6;
  const int wr = wid >> 1, wc = wid & 1;
  const int qr = lane & 15, g = lane >> 4;
  const int m0 = blockIdx.y * 128, n0 = blockIdx.x * 128;
  const int mode = blockIdx.z;
  const u16* Bt = WtAll + (size_t)mode * 1048576;
  const float* bias = (mode == 0) ? bq : (mode == 1) ? bk : bv;

  f32x4 acc[4][4];
  gemm_mainloop(A, Bt, m0, n0, As, Bs, acc);

  if (mode == 2) {
    // V transposed: Vt[b][h][dk][s], 4 consecutive s per lane -> 8B store
    #pragma unroll
    for (int i = 0; i < 4; i++) {
      const int mrow = m0 + wr*64 + i*16 + g*4;
      const int b = mrow >> 11, s = mrow & 2047;
      #pragma unroll
      for (int j = 0; j < 4; j++) {
        const int n = n0 + wc*64 + j*16 + qr;
        const float bz = bias[n];
        u16x4 v;
        #pragma unroll
        for (int r = 0; r < 4; r++) v[r] = f2bf(acc[i][j][r] + bz);
        *(u16x4*)&Vo[((size_t)(b*16 + (n >> 6))*64 + (n & 63))*2048 + s] = v;
      }
    }
  } else {
    u16* O = (mode == 0) ? Qo : Ko;         // [b][h][s][dk]
    #pragma unroll
    for (int i = 0; i < 4; i++) {
      const int mrow = m0 + wr*64 + i*16 + g*4;
      const int b = mrow >> 11, s = mrow & 2047;
      #pragma unroll
      for (int j = 0; j < 4; j++) {
        const int n = n0 + wc*64 + j*16 + qr;
        const float bz = bias[n];
        const size_t base = ((size_t)(b*16 + (n >> 6))*2048 + s)*64 + (n & 63);
        #pragma unroll
        for (int r = 0; r < 4; r++) O[base + (size_t)r*64] = f2bf(acc[i][j][r] + bz);
      }
    }
  }
}

// ---------------- flash attention v5: block-shared LDS K/V staging ----------------
// Theory (r5): the 248us wall was vector-memory REQUEST rate -- each wave issued
// 8 scattered 16-requests-per-instruction global loads/iter, and all 4 waves of
// a block loaded the SAME K/V (4x redundant). Now: K-tile (32x64) + V-tile
// (64x32) staged to LDS once per block via global_load_lds (2 calls/wave/iter,
// double-buffered), all waves read fragments from LDS.
// Swizzle (both-sides-or-neither, m173): global source chunk XOR'd with row
// bits, LDS dest linear, ds_read applies same XOR -> minimum bank aliasing.
__global__ __launch_bounds__(256, 4) void attn_kernel(
    const u16* __restrict__ Q, const u16* __restrict__ K,
    const u16* __restrict__ Vt, u16* __restrict__ cat)
{
  __shared__ __align__(16) u16 Ks[2][2048];   // [buf][32 t-rows][64 dk] (chunk-swizzled)
  __shared__ __align__(16) u16 Vs[2][2048];   // [buf][64 dk-rows][32 t] (chunk-swizzled)
  __shared__ __align__(16) u16 Pl[5120];      // 4 waves x 2 q-sets x [16 q][40] bf16
  const int lane = threadIdx.x & 63, w = threadIdx.x >> 6;
  const int bid = blockIdx.x;
  const int logical = (bid & 7) * 128 + (bid >> 3);  // XCD swizzle (1024 % 8 == 0)
  const int bh = logical >> 4;                 // b*16 + h
  const int xq = logical & 15;
  const int b = bh >> 4, h = bh & 15;
  const int q0 = xq * 128 + w * 32;            // 32 q-rows per wave
  const int qr = lane & 15, g = lane >> 4;
  u16* P0 = &Pl[(w*2 + 0)*640];
  u16* P1 = &Pl[(w*2 + 1)*640];

  const u16* Qb = Q  + (size_t)bh * 131072;   // [s][dk]
  const u16* Kb = K  + (size_t)bh * 131072;   // [t][dk]
  const u16* Vb = Vt + (size_t)bh * 131072;   // [dk][s]

  // staging source offsets (per-lane global, pre-swizzled; LDS dest linear)
  // K: wave w stages rows 8w..8w+7 (1KB contiguous region), chunk c^=row&7
  const int krow = 8*w + (lane >> 3), kc_ = lane & 7;
  const size_t ksrc = (size_t)krow*64 + (size_t)((kc_ ^ (lane >> 3)) * 8);
  // V: wave w stages dk-rows 16w..16w+15 (64B each from stride-4KB), chunk c^=row&3
  const int vrow = 16*w + (lane >> 2), vc_ = lane & 3;
  const size_t vsrc = (size_t)vrow*2048 + (size_t)((vc_ ^ ((lane >> 2) & 3)) * 8);

  // fragment read offsets (same XOR on read side)
  const int kro0 = qr*64        + ((g     ^ (qr & 7)) * 8);
  const int kro1 = qr*64        + (((4+g) ^ (qr & 7)) * 8);
  const int kro2 = (16+qr)*64   + ((g     ^ (qr & 7)) * 8);
  const int kro3 = (16+qr)*64   + (((4+g) ^ (qr & 7)) * 8);
  const int vro  = qr*32        + ((g ^ (qr & 3)) * 8);   // + d*512 per dk-tile

  const short8 qa0 = *(const short8*)&Qb[(size_t)(q0 + qr)*64 + g*8];
  const short8 qb0 = *(const short8*)&Qb[(size_t)(q0 + qr)*64 + 32 + g*8];
  const short8 qa1 = *(const short8*)&Qb[(size_t)(q0 + 16 + qr)*64 + g*8];
  const short8 qb1 = *(const short8*)&Qb[(size_t)(q0 + 16 + qr)*64 + 32 + g*8];

  f32x4 o0[4], o1[4];
  #pragma unroll
  for (int d = 0; d < 4; d++) { o0[d] = (f32x4){0.f,0.f,0.f,0.f}; o1[d] = (f32x4){0.f,0.f,0.f,0.f}; }
  float ps0 = 0.f, ps1 = 0.f;
  const float cexp = 0.125f * 1.44269504089f; // 1/sqrt(DK) folded into exp2

  // prologue: stage tile 0 into buf 0
  stage16(Kb + ksrc, &Ks[0][w*512]);
  stage16(Vb + vsrc, &Vs[0][w*512]);
  __syncthreads();

  for (int tt = 0; tt < 2048; tt += 32) {
    const int cur = (tt >> 5) & 1, nxt = cur ^ 1;
    // prefetch next tile into other buffer (wrap on last iter: harmless)
    const int tn = (tt + 32) & 2047;
    stage16(Kb + (size_t)tn*64 + ksrc, &Ks[nxt][w*512]);
    stage16(Vb + vsrc + tn,            &Vs[nxt][w*512]);

    // K fragments from LDS (shared by both q-sets)
    const u16* Kc = Ks[cur];
    short8 kc0 = *(const short8*)&Kc[kro0];
    short8 kc1 = *(const short8*)&Kc[kro1];
    short8 kc2 = *(const short8*)&Kc[kro2];
    short8 kc3 = *(const short8*)&Kc[kro3];

    f32x4 s00 = {0.f,0.f,0.f,0.f}, s01 = {0.f,0.f,0.f,0.f};
    f32x4 s10 = {0.f,0.f,0.f,0.f}, s11 = {0.f,0.f,0.f,0.f};
    s00 = __builtin_amdgcn_mfma_f32_16x16x32_bf16(kc0, qa0, s00, 0, 0, 0);
    s00 = __builtin_amdgcn_mfma_f32_16x16x32_bf16(kc1, qb0, s00, 0, 0, 0);
    s01 = __builtin_amdgcn_mfma_f32_16x16x32_bf16(kc2, qa0, s01, 0, 0, 0);
    s01 = __builtin_amdgcn_mfma_f32_16x16x32_bf16(kc3, qb0, s01, 0, 0, 0);
    s10 = __builtin_amdgcn_mfma_f32_16x16x32_bf16(kc0, qa1, s10, 0, 0, 0);
    s10 = __builtin_amdgcn_mfma_f32_16x16x32_bf16(kc1, qb1, s10, 0, 0, 0);
    s11 = __builtin_amdgcn_mfma_f32_16x16x32_bf16(kc2, qa1, s11, 0, 0, 0);
    s11 = __builtin_amdgcn_mfma_f32_16x16x32_bf16(kc3, qb1, s11, 0, 0, 0);

    // exp (no max subtraction: |scores| <= ~3), per-lane partial sums
    u16x4 lo0, hi0, lo1, hi1;
    #pragma unroll
    for (int r = 0; r < 4; r++) {
      float e;
      e = __builtin_amdgcn_exp2f(s00[r]*cexp); ps0 += e; lo0[r] = f2bf(e);
      e = __builtin_amdgcn_exp2f(s01[r]*cexp); ps0 += e; hi0[r] = f2bf(e);
      e = __builtin_amdgcn_exp2f(s10[r]*cexp); ps1 += e; lo1[r] = f2bf(e);
      e = __builtin_amdgcn_exp2f(s11[r]*cexp); ps1 += e; hi1[r] = f2bf(e);
    }
    // P^T redistribute via per-wave LDS round-trip (stride 40 bf16 = 80B rows)
    *(u16x4*)&P0[qr*40 + g*4]      = lo0;   // t = 4g..4g+3
    *(u16x4*)&P0[qr*40 + 16 + g*4] = hi0;   // t = 16+4g..16+4g+3
    *(u16x4*)&P1[qr*40 + g*4]      = lo1;
    *(u16x4*)&P1[qr*40 + 16 + g*4] = hi1;
    short8 bp0 = *(const short8*)&P0[qr*40 + g*8];  // t = 8g..8g+7, q = qr
    short8 bp1 = *(const short8*)&P1[qr*40 + g*8];

    // PV from LDS V-tile: heads^T[dk][q] += V^T[dk][t] . P^T[t][q]
    const u16* Vc = Vs[cur];
    #pragma unroll
    for (int d = 0; d < 4; d++) {
      short8 av = *(const short8*)&Vc[d*512 + vro];
      o0[d] = __builtin_amdgcn_mfma_f32_16x16x32_bf16(av, bp0, o0[d], 0, 0, 0);
      o1[d] = __builtin_amdgcn_mfma_f32_16x16x32_bf16(av, bp1, o1[d], 0, 0, 0);
    }
    __syncthreads();   // drains vmcnt (staging) + lgkmcnt; next tile ready
  }
  float l0 = ps0; l0 += __shfl_xor(l0, 16); l0 += __shfl_xor(l0, 32);
  float l1 = ps1; l1 += __shfl_xor(l1, 16); l1 += __shfl_xor(l1, 32);
  const float inv0 = 1.0f / l0, inv1 = 1.0f / l1;
  const size_t base0 = ((size_t)(b*2048 + q0 + qr))*1024 + h*64;
  const size_t base1 = ((size_t)(b*2048 + q0 + 16 + qr))*1024 + h*64;
  #pragma unroll
  for (int d = 0; d < 4; d++) {
    u16x4 v0, v1;
    #pragma unroll
    for (int r = 0; r < 4; r++) { v0[r] = f2bf(o0[d][r] * inv0); v1[r] = f2bf(o1[d][r] * inv1); }
    *(u16x4*)&cat[base0 + d*16 + g*4] = v0;
    *(u16x4*)&cat[base1 + d*16 + g*4] = v1;
  }
}

// ---------------- output projection: f32 out + bias ----------------
__global__ __launch_bounds__(256) void out_gemm_kernel(
    const u16* __restrict__ A, const u16* __restrict__ Bt,
    const float* __restrict__ bias, float* __restrict__ out)
{
  __shared__ __align__(128) u16 As[4096];
  __shared__ __align__(128) u16 Bs[4096];
  const int lane = threadIdx.x & 63, wid = threadIdx.x >> 6;
  const int wr = wid >> 1, wc = wid & 1;
  const int qr = lane & 15, g = lane >> 4;
  const int m0 = blockIdx.y * 128, n0 = blockIdx.x * 128;

  f32x4 acc[4][4];
  gemm_mainloop(A, Bt, m0, n0, As, Bs, acc);

  #pragma unroll
  for (int i = 0; i < 4; i++) {
    const int mrow = m0 + wr*64 + i*16 + g*4;
    #pragma unroll
    for (int j = 0; j < 4; j++) {
      const int n = n0 + wc*64 + j*16 + qr;
      const float bz = bias[n];
      #pragma unroll
      for (int r = 0; r < 4; r++) out[(size_t)(mrow + r)*1024 + n] = acc[i][j][r] + bz;
    }
  }
}

extern "C" void kernel_launch(void* const* d_in, const int* in_sizes, int n_in,
                              void* d_out, int out_size, void* d_ws, size_t ws_size,
                              hipStream_t stream) {
  const float* x  = (const float*)d_in[0];
  const float* Wq = (const float*)d_in[1];
  const float* bq = (const float*)d_in[2];
  const float* Wk = (const float*)d_in[3];
  const float* bk = (const float*)d_in[4];
  const float* Wv = (const float*)d_in[5];
  const float* bv = (const float*)d_in[6];
  const float* Wo = (const float*)d_in[7];
  const float* bo = (const float*)d_in[8];
  float* out = (float*)d_out;
  char* ws = (char*)d_ws;

  // workspace layout (bytes): xb 16M (reused as cat) | Wt 6M | Wot 2M | Q 16M | K 16M | Vt 16M
  u16* xb  = (u16*)(ws);
  u16* Wt  = (u16*)(ws + 16777216);
  u16* Wot = (u16*)(ws + 23068672);
  u16* Qb  = (u16*)(ws + 25165824);
  u16* Kb  = (u16*)(ws + 41943040);
  u16* Vt  = (u16*)(ws + 58720256);
  u16* cat = xb;  // xb dead after qkv_gemm; attn writes cat there

  cvt_kernel<<<8192, 256, 0, stream>>>(x, Wq, Wk, Wv, Wo, xb, Wt, Wot);
  qkv_gemm_kernel<<<dim3(8, 64, 3), 256, 0, stream>>>(xb, Wt, bq, bk, bv, Qb, Kb, Vt);
  attn_kernel<<<1024, 256, 0, stream>>>(Qb, Kb, Vt, cat);
  out_gemm_kernel<<<dim3(8, 64), 256, 0, stream>>>(cat, Wot, bo, out);
}

// Round 7
// 219.230 us; speedup vs baseline: 2.7224x; 1.0632x over previous
//
#include <hip/hip_runtime.h>
#include <hip/hip_bf16.h>
#include <stdint.h>

typedef unsigned short u16;
typedef __attribute__((ext_vector_type(8))) short short8;   // 8 bf16 (4 VGPRs) MFMA A/B frag
typedef __attribute__((ext_vector_type(4))) float f32x4;    // MFMA C/D frag
typedef __attribute__((ext_vector_type(4))) unsigned short u16x4;

#define DEV static __device__ __forceinline__

// B=4, S=2048, D=1024, H=16, DK=64, DOUT=1024; M = B*S = 8192

DEV u16 f2bf(float f) {  // f32 -> bf16 RNE (compiler emits v_cvt_pk_bf16_f32 for pairs)
  __hip_bfloat16 b = __float2bfloat16(f);
  return *(u16*)&b;
}

DEV void stage16(const u16* g, u16* l) {
  // async global->LDS, 16B per lane; LDS dest = wave-uniform base + lane*16
  __builtin_amdgcn_global_load_lds((const __attribute__((address_space(1))) void*)g,
                                   (__attribute__((address_space(3))) void*)l, 16, 0, 0);
}

// ---------------- conversions / transposes (one launch) ----------------
__global__ __launch_bounds__(256) void cvt_kernel(
    const float* __restrict__ x, const float* __restrict__ Wq,
    const float* __restrict__ Wk, const float* __restrict__ Wv,
    const float* __restrict__ Wo,
    u16* __restrict__ xb, u16* __restrict__ Wt, u16* __restrict__ Wot)
{
  int idx = blockIdx.x * 256 + threadIdx.x;
  if (idx < 1048576) {                      // x: [8192][1024] f32 -> bf16, 8 elems/thread
    int i = idx * 8;
    f32x4 v0 = *(const f32x4*)&x[i];
    f32x4 v1 = *(const f32x4*)&x[i + 4];
    short8 o;
    o[0]=f2bf(v0[0]); o[1]=f2bf(v0[1]); o[2]=f2bf(v0[2]); o[3]=f2bf(v0[3]);
    o[4]=f2bf(v1[0]); o[5]=f2bf(v1[1]); o[6]=f2bf(v1[2]); o[7]=f2bf(v1[3]);
    *(short8*)&xb[i] = o;
  } else if (idx < 1835008) {               // Wq/Wk/Wv [H][D][DK] -> Wt[w][n=h*64+k][d]
    int t = (idx - 1048576) * 4;
    int w = t >> 20; int r = t & 1048575; int n = r >> 10; int d0 = r & 1023;
    const float* W = (w == 0) ? Wq : (w == 1) ? Wk : Wv;
    int h = n >> 6, k = n & 63;
    u16x4 o;
    #pragma unroll
    for (int u = 0; u < 4; u++) o[u] = f2bf(W[(size_t)(h*1024 + d0 + u)*64 + k]);
    *(u16x4*)&Wt[t] = o;
  } else if (idx < 2097152) {               // Wo [f][n] -> Wot[n][f]
    int t = (idx - 1835008) * 4;
    int n = t >> 10, d0 = t & 1023;
    u16x4 o;
    #pragma unroll
    for (int u = 0; u < 4; u++) o[u] = f2bf(Wo[(size_t)(d0 + u)*1024 + n]);
    *(u16x4*)&Wot[t] = o;
  }
}

// ---------------- shared GEMM main loop (128x128 tile, BK=32, 4 waves) ----------------
DEV void gemm_mainloop(const u16* __restrict__ A, const u16* __restrict__ Bt,
                       int m0, int n0, u16* As, u16* Bs, f32x4 acc[4][4])
{
  const int tid = threadIdx.x;
  const int lane = tid & 63, wid = tid >> 6;
  const int wr = wid >> 1, wc = wid & 1;
  const int qr = lane & 15, g = lane >> 4;
  const int c0 = wid * 2, rA = lane >> 2, cA = (lane & 3) * 8;

  #pragma unroll
  for (int i = 0; i < 4; i++)
    #pragma unroll
    for (int j = 0; j < 4; j++) acc[i][j] = (f32x4){0.f, 0.f, 0.f, 0.f};

  for (int kt = 0; kt < 1024; kt += 32) {
    #pragma unroll
    for (int q = 0; q < 2; q++) {
      const int c = c0 + q;                 // chunk of 16 rows (1KB LDS)
      stage16(A  + (size_t)(m0 + c*16 + rA)*1024 + kt + cA, &As[c*512]);
      stage16(Bt + (size_t)(n0 + c*16 + rA)*1024 + kt + cA, &Bs[c*512]);
    }
    __syncthreads();
    short8 af[4], bfr[4];
    #pragma unroll
    for (int i = 0; i < 4; i++) af[i]  = *(const short8*)&As[(wr*64 + i*16 + qr)*32 + g*8];
    #pragma unroll
    for (int j = 0; j < 4; j++) bfr[j] = *(const short8*)&Bs[(wc*64 + j*16 + qr)*32 + g*8];
    #pragma unroll
    for (int i = 0; i < 4; i++)
      #pragma unroll
      for (int j = 0; j < 4; j++)
        acc[i][j] = __builtin_amdgcn_mfma_f32_16x16x32_bf16(af[i], bfr[j], acc[i][j], 0, 0, 0);
    __syncthreads();
  }
}

// ---------------- QKV projection: z picks Q/K/V ----------------
// Q output is PRE-SCALED by 0.125*log2(e) so attn can use exp2 on raw scores.
__global__ __launch_bounds__(256) void qkv_gemm_kernel(
    const u16* __restrict__ A, const u16* __restrict__ WtAll,
    const float* __restrict__ bq, const float* __restrict__ bk, const float* __restrict__ bv,
    u16* __restrict__ Qo, u16* __restrict__ Ko, u16* __restrict__ Vo)
{
  __shared__ __align__(128) u16 As[4096];
  __shared__ __align__(128) u16 Bs[4096];
  const int lane = threadIdx.x & 63, wid = threadIdx.x >> 6;
  const int wr = wid >> 1, wc = wid & 1;
  const int qr = lane & 15, g = lane >> 4;
  const int m0 = blockIdx.y * 128, n0 = blockIdx.x * 128;
  const int mode = blockIdx.z;
  const u16* Bt = WtAll + (size_t)mode * 1048576;
  const float* bias = (mode == 0) ? bq : (mode == 1) ? bk : bv;
  const float osc = (mode == 0) ? 0.1803368867f : 1.0f;  // 0.125*log2e folded into Q

  f32x4 acc[4][4];
  gemm_mainloop(A, Bt, m0, n0, As, Bs, acc);

  if (mode == 2) {
    // V transposed: Vt[b][h][dk][s], 4 consecutive s per lane -> 8B store
    #pragma unroll
    for (int i = 0; i < 4; i++) {
      const int mrow = m0 + wr*64 + i*16 + g*4;
      const int b = mrow >> 11, s = mrow & 2047;
      #pragma unroll
      for (int j = 0; j < 4; j++) {
        const int n = n0 + wc*64 + j*16 + qr;
        const float bz = bias[n];
        u16x4 v;
        #pragma unroll
        for (int r = 0; r < 4; r++) v[r] = f2bf(acc[i][j][r] + bz);
        *(u16x4*)&Vo[((size_t)(b*16 + (n >> 6))*64 + (n & 63))*2048 + s] = v;
      }
    }
  } else {
    u16* O = (mode == 0) ? Qo : Ko;         // [b][h][s][dk]
    #pragma unroll
    for (int i = 0; i < 4; i++) {
      const int mrow = m0 + wr*64 + i*16 + g*4;
      const int b = mrow >> 11, s = mrow & 2047;
      #pragma unroll
      for (int j = 0; j < 4; j++) {
        const int n = n0 + wc*64 + j*16 + qr;
        const float bz = bias[n];
        const size_t base = ((size_t)(b*16 + (n >> 6))*2048 + s)*64 + (n & 63);
        #pragma unroll
        for (int r = 0; r < 4; r++) O[base + (size_t)r*64] = f2bf((acc[i][j][r] + bz) * osc);
      }
    }
  }
}

// ---------------- flash attention v6: VALU diet ----------------
// vs v5: (a) Q pre-scaled in qkv epilogue -> exp2(s) directly, 16 muls/iter gone;
// (b) softmax denominator l computed by MFMA with an all-ones A-fragment
//     (2 MFMA/iter replace 32 v_add/iter, and the D-frag gives every lane l for
//     its own output column -> final shfl_xor reduce gone too).
__global__ __launch_bounds__(256, 4) void attn_kernel(
    const u16* __restrict__ Q, const u16* __restrict__ K,
    const u16* __restrict__ Vt, u16* __restrict__ cat)
{
  __shared__ __align__(16) u16 Ks[2][2048];   // [buf][32 t-rows][64 dk] (chunk-swizzled)
  __shared__ __align__(16) u16 Vs[2][2048];   // [buf][64 dk-rows][32 t] (chunk-swizzled)
  __shared__ __align__(16) u16 Pl[5120];      // 4 waves x 2 q-sets x [16 q][40] bf16
  const int lane = threadIdx.x & 63, w = threadIdx.x >> 6;
  const int bid = blockIdx.x;
  const int logical = (bid & 7) * 128 + (bid >> 3);  // XCD swizzle (1024 % 8 == 0)
  const int bh = logical >> 4;                 // b*16 + h
  const int xq = logical & 15;
  const int b = bh >> 4, h = bh & 15;
  const int q0 = xq * 128 + w * 32;            // 32 q-rows per wave
  const int qr = lane & 15, g = lane >> 4;
  u16* P0 = &Pl[(w*2 + 0)*640];
  u16* P1 = &Pl[(w*2 + 1)*640];

  const u16* Qb = Q  + (size_t)bh * 131072;   // [s][dk]
  const u16* Kb = K  + (size_t)bh * 131072;   // [t][dk]
  const u16* Vb = Vt + (size_t)bh * 131072;   // [dk][s]

  // staging source offsets (per-lane global, pre-swizzled; LDS dest linear)
  const int krow = 8*w + (lane >> 3), kc_ = lane & 7;
  const size_t ksrc = (size_t)krow*64 + (size_t)((kc_ ^ (lane >> 3)) * 8);
  const int vrow = 16*w + (lane >> 2), vc_ = lane & 3;
  const size_t vsrc = (size_t)vrow*2048 + (size_t)((vc_ ^ ((lane >> 2) & 3)) * 8);

  // fragment read offsets (same XOR on read side)
  const int kro0 = qr*64        + ((g     ^ (qr & 7)) * 8);
  const int kro1 = qr*64        + (((4+g) ^ (qr & 7)) * 8);
  const int kro2 = (16+qr)*64   + ((g     ^ (qr & 7)) * 8);
  const int kro3 = (16+qr)*64   + (((4+g) ^ (qr & 7)) * 8);
  const int vro  = qr*32        + ((g ^ (qr & 3)) * 8);   // + d*512 per dk-tile

  const short8 qa0 = *(const short8*)&Qb[(size_t)(q0 + qr)*64 + g*8];
  const short8 qb0 = *(const short8*)&Qb[(size_t)(q0 + qr)*64 + 32 + g*8];
  const short8 qa1 = *(const short8*)&Qb[(size_t)(q0 + 16 + qr)*64 + g*8];
  const short8 qb1 = *(const short8*)&Qb[(size_t)(q0 + 16 + qr)*64 + 32 + g*8];

  const short ONE = (short)0x3F80;            // bf16 1.0
  const short8 ones = {ONE, ONE, ONE, ONE, ONE, ONE, ONE, ONE};

  f32x4 o0[4], o1[4];
  #pragma unroll
  for (int d = 0; d < 4; d++) { o0[d] = (f32x4){0.f,0.f,0.f,0.f}; o1[d] = (f32x4){0.f,0.f,0.f,0.f}; }
  f32x4 ol0 = {0.f,0.f,0.f,0.f}, ol1 = {0.f,0.f,0.f,0.f};

  // prologue: stage tile 0 into buf 0
  stage16(Kb + ksrc, &Ks[0][w*512]);
  stage16(Vb + vsrc, &Vs[0][w*512]);
  __syncthreads();

  for (int tt = 0; tt < 2048; tt += 32) {
    const int cur = (tt >> 5) & 1, nxt = cur ^ 1;
    // prefetch next tile into other buffer (wrap on last iter: harmless)
    const int tn = (tt + 32) & 2047;
    stage16(Kb + (size_t)tn*64 + ksrc, &Ks[nxt][w*512]);
    stage16(Vb + vsrc + tn,            &Vs[nxt][w*512]);

    // K fragments from LDS (shared by both q-sets)
    const u16* Kc = Ks[cur];
    short8 kc0 = *(const short8*)&Kc[kro0];
    short8 kc1 = *(const short8*)&Kc[kro1];
    short8 kc2 = *(const short8*)&Kc[kro2];
    short8 kc3 = *(const short8*)&Kc[kro3];

    f32x4 s00 = {0.f,0.f,0.f,0.f}, s01 = {0.f,0.f,0.f,0.f};
    f32x4 s10 = {0.f,0.f,0.f,0.f}, s11 = {0.f,0.f,0.f,0.f};
    s00 = __builtin_amdgcn_mfma_f32_16x16x32_bf16(kc0, qa0, s00, 0, 0, 0);
    s00 = __builtin_amdgcn_mfma_f32_16x16x32_bf16(kc1, qb0, s00, 0, 0, 0);
    s01 = __builtin_amdgcn_mfma_f32_16x16x32_bf16(kc2, qa0, s01, 0, 0, 0);
    s01 = __builtin_amdgcn_mfma_f32_16x16x32_bf16(kc3, qb0, s01, 0, 0, 0);
    s10 = __builtin_amdgcn_mfma_f32_16x16x32_bf16(kc0, qa1, s10, 0, 0, 0);
    s10 = __builtin_amdgcn_mfma_f32_16x16x32_bf16(kc1, qb1, s10, 0, 0, 0);
    s11 = __builtin_amdgcn_mfma_f32_16x16x32_bf16(kc2, qa1, s11, 0, 0, 0);
    s11 = __builtin_amdgcn_mfma_f32_16x16x32_bf16(kc3, qb1, s11, 0, 0, 0);

    // exp2 (Q pre-scaled; |scores| small so no max subtraction)
    u16x4 lo0, hi0, lo1, hi1;
    #pragma unroll
    for (int r = 0; r < 4; r++) {
      lo0[r] = f2bf(__builtin_amdgcn_exp2f(s00[r]));
      hi0[r] = f2bf(__builtin_amdgcn_exp2f(s01[r]));
      lo1[r] = f2bf(__builtin_amdgcn_exp2f(s10[r]));
      hi1[r] = f2bf(__builtin_amdgcn_exp2f(s11[r]));
    }
    // P^T redistribute via per-wave LDS round-trip (stride 40 bf16 = 80B rows)
    *(u16x4*)&P0[qr*40 + g*4]      = lo0;   // t = 4g..4g+3
    *(u16x4*)&P0[qr*40 + 16 + g*4] = hi0;   // t = 16+4g..16+4g+3
    *(u16x4*)&P1[qr*40 + g*4]      = lo1;
    *(u16x4*)&P1[qr*40 + 16 + g*4] = hi1;
    short8 bp0 = *(const short8*)&P0[qr*40 + g*8];  // t = 8g..8g+7, q = qr
    short8 bp1 = *(const short8*)&P1[qr*40 + g*8];

    // denominator via MFMA: ol[i][q] += sum_t P^T[t][q]  (ones A-frag)
    ol0 = __builtin_amdgcn_mfma_f32_16x16x32_bf16(ones, bp0, ol0, 0, 0, 0);
    ol1 = __builtin_amdgcn_mfma_f32_16x16x32_bf16(ones, bp1, ol1, 0, 0, 0);

    // PV from LDS V-tile: heads^T[dk][q] += V^T[dk][t] . P^T[t][q]
    const u16* Vc = Vs[cur];
    #pragma unroll
    for (int d = 0; d < 4; d++) {
      short8 av = *(const short8*)&Vc[d*512 + vro];
      o0[d] = __builtin_amdgcn_mfma_f32_16x16x32_bf16(av, bp0, o0[d], 0, 0, 0);
      o1[d] = __builtin_amdgcn_mfma_f32_16x16x32_bf16(av, bp1, o1[d], 0, 0, 0);
    }
    __syncthreads();   // drains vmcnt (staging) + lgkmcnt; next tile ready
  }
  // every lane's D-frag column is qr -> ol[0] IS l for this lane's outputs
  const float inv0 = 1.0f / ol0[0], inv1 = 1.0f / ol1[0];
  const size_t base0 = ((size_t)(b*2048 + q0 + qr))*1024 + h*64;
  const size_t base1 = ((size_t)(b*2048 + q0 + 16 + qr))*1024 + h*64;
  #pragma unroll
  for (int d = 0; d < 4; d++) {
    u16x4 v0, v1;
    #pragma unroll
    for (int r = 0; r < 4; r++) { v0[r] = f2bf(o0[d][r] * inv0); v1[r] = f2bf(o1[d][r] * inv1); }
    *(u16x4*)&cat[base0 + d*16 + g*4] = v0;
    *(u16x4*)&cat[base1 + d*16 + g*4] = v1;
  }
}

// ---------------- output projection: f32 out + bias ----------------
__global__ __launch_bounds__(256) void out_gemm_kernel(
    const u16* __restrict__ A, const u16* __restrict__ Bt,
    const float* __restrict__ bias, float* __restrict__ out)
{
  __shared__ __align__(128) u16 As[4096];
  __shared__ __align__(128) u16 Bs[4096];
  const int lane = threadIdx.x & 63, wid = threadIdx.x >> 6;
  const int wr = wid >> 1, wc = wid & 1;
  const int qr = lane & 15, g = lane >> 4;
  const int m0 = blockIdx.y * 128, n0 = blockIdx.x * 128;

  f32x4 acc[4][4];
  gemm_mainloop(A, Bt, m0, n0, As, Bs, acc);

  #pragma unroll
  for (int i = 0; i < 4; i++) {
    const int mrow = m0 + wr*64 + i*16 + g*4;
    #pragma unroll
    for (int j = 0; j < 4; j++) {
      const int n = n0 + wc*64 + j*16 + qr;
      const float bz = bias[n];
      #pragma unroll
      for (int r = 0; r < 4; r++) out[(size_t)(mrow + r)*1024 + n] = acc[i][j][r] + bz;
    }
  }
}

extern "C" void kernel_launch(void* const* d_in, const int* in_sizes, int n_in,
                              void* d_out, int out_size, void* d_ws, size_t ws_size,
                              hipStream_t stream) {
  const float* x  = (const float*)d_in[0];
  const float* Wq = (const float*)d_in[1];
  const float* bq = (const float*)d_in[2];
  const float* Wk = (const float*)d_in[3];
  const float* bk = (const float*)d_in[4];
  const float* Wv = (const float*)d_in[5];
  const float* bv = (const float*)d_in[6];
  const float* Wo = (const float*)d_in[7];
  const float* bo = (const float*)d_in[8];
  float* out = (float*)d_out;
  char* ws = (char*)d_ws;

  // workspace layout (bytes): xb 16M (reused as cat) | Wt 6M | Wot 2M | Q 16M | K 16M | Vt 16M
  u16* xb  = (u16*)(ws);
  u16* Wt  = (u16*)(ws + 16777216);
  u16* Wot = (u16*)(ws + 23068672);
  u16* Qb  = (u16*)(ws + 25165824);
  u16* Kb  = (u16*)(ws + 41943040);
  u16* Vt  = (u16*)(ws + 58720256);
  u16* cat = xb;  // xb dead after qkv_gemm; attn writes cat there

  cvt_kernel<<<8192, 256, 0, stream>>>(x, Wq, Wk, Wv, Wo, xb, Wt, Wot);
  qkv_gemm_kernel<<<dim3(8, 64, 3), 256, 0, stream>>>(xb, Wt, bq, bk, bv, Qb, Kb, Vt);
  attn_kernel<<<1024, 256, 0, stream>>>(Qb, Kb, Vt, cat);
  out_gemm_kernel<<<dim3(8, 64), 256, 0, stream>>>(cat, Wot, bo, out);
}

// Round 8
// 202.147 us; speedup vs baseline: 2.9525x; 1.0845x over previous
//
#include <hip/hip_runtime.h>
#include <hip/hip_bf16.h>
#include <stdint.h>

typedef unsigned short u16;
typedef __attribute__((ext_vector_type(8))) short short8;   // 8 bf16 (4 VGPRs) MFMA A/B frag
typedef __attribute__((ext_vector_type(4))) float f32x4;    // MFMA C/D frag
typedef __attribute__((ext_vector_type(4))) unsigned short u16x4;

#define DEV static __device__ __forceinline__

// B=4, S=2048, D=1024, H=16, DK=64, DOUT=1024; M = B*S = 8192

DEV u16 f2bf(float f) {  // f32 -> bf16 RNE (compiler emits v_cvt_pk_bf16_f32 for pairs)
  __hip_bfloat16 b = __float2bfloat16(f);
  return *(u16*)&b;
}

DEV void stage16(const u16* g, u16* l) {
  // async global->LDS, 16B per lane; LDS dest = wave-uniform base + lane*16
  __builtin_amdgcn_global_load_lds((const __attribute__((address_space(1))) void*)g,
                                   (__attribute__((address_space(3))) void*)l, 16, 0, 0);
}

// ---------------- conversions / transposes (one launch) ----------------
__global__ __launch_bounds__(256) void cvt_kernel(
    const float* __restrict__ x, const float* __restrict__ Wq,
    const float* __restrict__ Wk, const float* __restrict__ Wv,
    const float* __restrict__ Wo,
    u16* __restrict__ xb, u16* __restrict__ Wt, u16* __restrict__ Wot)
{
  int idx = blockIdx.x * 256 + threadIdx.x;
  if (idx < 1048576) {                      // x: [8192][1024] f32 -> bf16, 8 elems/thread
    int i = idx * 8;
    f32x4 v0 = *(const f32x4*)&x[i];
    f32x4 v1 = *(const f32x4*)&x[i + 4];
    short8 o;
    o[0]=f2bf(v0[0]); o[1]=f2bf(v0[1]); o[2]=f2bf(v0[2]); o[3]=f2bf(v0[3]);
    o[4]=f2bf(v1[0]); o[5]=f2bf(v1[1]); o[6]=f2bf(v1[2]); o[7]=f2bf(v1[3]);
    *(short8*)&xb[i] = o;
  } else if (idx < 1835008) {               // Wq/Wk/Wv [H][D][DK] -> Wt[w][n=h*64+k][d]
    int t = (idx - 1048576) * 4;
    int w = t >> 20; int r = t & 1048575; int n = r >> 10; int d0 = r & 1023;
    const float* W = (w == 0) ? Wq : (w == 1) ? Wk : Wv;
    int h = n >> 6, k = n & 63;
    u16x4 o;
    #pragma unroll
    for (int u = 0; u < 4; u++) o[u] = f2bf(W[(size_t)(h*1024 + d0 + u)*64 + k]);
    *(u16x4*)&Wt[t] = o;
  } else if (idx < 2097152) {               // Wo [f][n] -> Wot[n][f]
    int t = (idx - 1835008) * 4;
    int n = t >> 10, d0 = t & 1023;
    u16x4 o;
    #pragma unroll
    for (int u = 0; u < 4; u++) o[u] = f2bf(Wo[(size_t)(d0 + u)*1024 + n]);
    *(u16x4*)&Wot[t] = o;
  }
}

// ---------------- shared GEMM main loop (128x128 tile, BK=32, 4 waves) ----------------
DEV void gemm_mainloop(const u16* __restrict__ A, const u16* __restrict__ Bt,
                       int m0, int n0, u16* As, u16* Bs, f32x4 acc[4][4])
{
  const int tid = threadIdx.x;
  const int lane = tid & 63, wid = tid >> 6;
  const int wr = wid >> 1, wc = wid & 1;
  const int qr = lane & 15, g = lane >> 4;
  const int c0 = wid * 2, rA = lane >> 2, cA = (lane & 3) * 8;

  #pragma unroll
  for (int i = 0; i < 4; i++)
    #pragma unroll
    for (int j = 0; j < 4; j++) acc[i][j] = (f32x4){0.f, 0.f, 0.f, 0.f};

  for (int kt = 0; kt < 1024; kt += 32) {
    #pragma unroll
    for (int q = 0; q < 2; q++) {
      const int c = c0 + q;                 // chunk of 16 rows (1KB LDS)
      stage16(A  + (size_t)(m0 + c*16 + rA)*1024 + kt + cA, &As[c*512]);
      stage16(Bt + (size_t)(n0 + c*16 + rA)*1024 + kt + cA, &Bs[c*512]);
    }
    __syncthreads();
    short8 af[4], bfr[4];
    #pragma unroll
    for (int i = 0; i < 4; i++) af[i]  = *(const short8*)&As[(wr*64 + i*16 + qr)*32 + g*8];
    #pragma unroll
    for (int j = 0; j < 4; j++) bfr[j] = *(const short8*)&Bs[(wc*64 + j*16 + qr)*32 + g*8];
    #pragma unroll
    for (int i = 0; i < 4; i++)
      #pragma unroll
      for (int j = 0; j < 4; j++)
        acc[i][j] = __builtin_amdgcn_mfma_f32_16x16x32_bf16(af[i], bfr[j], acc[i][j], 0, 0, 0);
    __syncthreads();
  }
}

// ---------------- QKV projection: z picks Q/K/V ----------------
// Q output is PRE-SCALED by 0.125*log2(e) so attn can use exp2 on raw scores.
__global__ __launch_bounds__(256) void qkv_gemm_kernel(
    const u16* __restrict__ A, const u16* __restrict__ WtAll,
    const float* __restrict__ bq, const float* __restrict__ bk, const float* __restrict__ bv,
    u16* __restrict__ Qo, u16* __restrict__ Ko, u16* __restrict__ Vo)
{
  __shared__ __align__(128) u16 As[4096];
  __shared__ __align__(128) u16 Bs[4096];
  const int lane = threadIdx.x & 63, wid = threadIdx.x >> 6;
  const int wr = wid >> 1, wc = wid & 1;
  const int qr = lane & 15, g = lane >> 4;
  const int m0 = blockIdx.y * 128, n0 = blockIdx.x * 128;
  const int mode = blockIdx.z;
  const u16* Bt = WtAll + (size_t)mode * 1048576;
  const float* bias = (mode == 0) ? bq : (mode == 1) ? bk : bv;
  const float osc = (mode == 0) ? 0.1803368867f : 1.0f;  // 0.125*log2e folded into Q

  f32x4 acc[4][4];
  gemm_mainloop(A, Bt, m0, n0, As, Bs, acc);

  if (mode == 2) {
    // V transposed: Vt[b][h][dk][s], 4 consecutive s per lane -> 8B store
    #pragma unroll
    for (int i = 0; i < 4; i++) {
      const int mrow = m0 + wr*64 + i*16 + g*4;
      const int b = mrow >> 11, s = mrow & 2047;
      #pragma unroll
      for (int j = 0; j < 4; j++) {
        const int n = n0 + wc*64 + j*16 + qr;
        const float bz = bias[n];
        u16x4 v;
        #pragma unroll
        for (int r = 0; r < 4; r++) v[r] = f2bf(acc[i][j][r] + bz);
        *(u16x4*)&Vo[((size_t)(b*16 + (n >> 6))*64 + (n & 63))*2048 + s] = v;
      }
    }
  } else {
    u16* O = (mode == 0) ? Qo : Ko;         // [b][h][s][dk]
    #pragma unroll
    for (int i = 0; i < 4; i++) {
      const int mrow = m0 + wr*64 + i*16 + g*4;
      const int b = mrow >> 11, s = mrow & 2047;
      #pragma unroll
      for (int j = 0; j < 4; j++) {
        const int n = n0 + wc*64 + j*16 + qr;
        const float bz = bias[n];
        const size_t base = ((size_t)(b*16 + (n >> 6))*2048 + s)*64 + (n & 63);
        #pragma unroll
        for (int r = 0; r < 4; r++) O[base + (size_t)r*64] = f2bf((acc[i][j][r] + bz) * osc);
      }
    }
  }
}

// ---------------- flash attention v7: amortize K/V LDS reads over 64 q/wave ----------------
// r7 diagnosis: LDS BW-bound (224KB/CU/iter; K/V frag reads 4x redundant across
// waves). Now: 8-wave blocks, each wave owns 64 q (4 q-sets); K/V tile staged
// once per 8 waves (1 stage16/wave/iter); per-CU LDS traffic ~136KB/iter and
// MFMA work/iter doubles -> MFMA-bound regime. Grid 64bh x 4qtile = 256 = 1/CU.
// V bank swizzle fixed: rows stride 64B (16 banks) -> XOR must use (row>>1)&3
// (old row&3 left 4-way conflicts). K XOR (row&7) unchanged (128B rows).
__global__ __launch_bounds__(512, 2) void attn_kernel(
    const u16* __restrict__ Q, const u16* __restrict__ K,
    const u16* __restrict__ Vt, u16* __restrict__ cat)
{
  __shared__ __align__(16) u16 Ks[2][2048];   // [buf][32 t][64 dk] (chunk-swizzled)
  __shared__ __align__(16) u16 Vs[2][2048];   // [buf][64 dk][32 t] (chunk-swizzled)
  __shared__ __align__(16) u16 Pl[10240];     // 8 waves x 2 bufs x [16 q][40] bf16
  const int lane = threadIdx.x & 63, w = threadIdx.x >> 6;
  const int bid = blockIdx.x;
  const int logical = (bid & 7) * 32 + (bid >> 3);  // XCD swizzle (256 % 8 == 0)
  const int bh = logical >> 2;                 // b*16 + h
  const int xq = logical & 3;
  const int b = bh >> 4, h = bh & 15;
  const int q0 = xq * 512 + w * 64;            // 64 q-rows per wave (4 q-sets)
  const int qr = lane & 15, g = lane >> 4;
  u16* P0 = &Pl[(w*2 + 0)*640];
  u16* P1 = &Pl[(w*2 + 1)*640];

  const u16* Qb = Q  + (size_t)bh * 131072;   // [s][dk]
  const u16* Kb = K  + (size_t)bh * 131072;   // [t][dk]
  const u16* Vb = Vt + (size_t)bh * 131072;   // [dk][s]

  // staging: waves 0-3 stage K rows 8w..8w+7; waves 4-7 stage V dk-rows 16(w-4)..+15
  const int isK = (w < 4);
  const int krow = 8*w + (lane >> 3);
  const size_t ksrc = (size_t)krow*64 + (size_t)(((lane & 7) ^ (lane >> 3)) * 8);
  const int vw = w - 4, vrow = 16*vw + (lane >> 2);
  const size_t vsrc = (size_t)vrow*2048 + (size_t)(((lane & 3) ^ ((lane >> 3) & 3)) * 8);
  u16* kdst0 = &Ks[0][w*512];       u16* kdst1 = &Ks[1][w*512];
  u16* vdst0 = &Vs[0][vw*512];      u16* vdst1 = &Vs[1][vw*512];

  // fragment read offsets (same XOR on read side)
  const int kro0 = qr*64        + ((g     ^ (qr & 7)) * 8);
  const int kro1 = qr*64        + (((4+g) ^ (qr & 7)) * 8);
  const int kro2 = (16+qr)*64   + ((g     ^ (qr & 7)) * 8);
  const int kro3 = (16+qr)*64   + (((4+g) ^ (qr & 7)) * 8);
  const int vro  = qr*32        + ((g ^ ((qr >> 1) & 3)) * 8);   // + d*512 per dk-tile

  short8 qa[4], qb_[4];
  #pragma unroll
  for (int qs = 0; qs < 4; qs++) {
    qa[qs]  = *(const short8*)&Qb[(size_t)(q0 + qs*16 + qr)*64 + g*8];
    qb_[qs] = *(const short8*)&Qb[(size_t)(q0 + qs*16 + qr)*64 + 32 + g*8];
  }

  const short ONE = (short)0x3F80;            // bf16 1.0
  const short8 ones = {ONE, ONE, ONE, ONE, ONE, ONE, ONE, ONE};

  f32x4 o[4][4];                              // [qset][dk-tile]
  #pragma unroll
  for (int qs = 0; qs < 4; qs++)
    #pragma unroll
    for (int d = 0; d < 4; d++) o[qs][d] = (f32x4){0.f,0.f,0.f,0.f};
  f32x4 ol[4] = {{0.f,0.f,0.f,0.f},{0.f,0.f,0.f,0.f},{0.f,0.f,0.f,0.f},{0.f,0.f,0.f,0.f}};

  // prologue: stage tile 0 into buf 0
  if (isK) stage16(Kb + ksrc, kdst0); else stage16(Vb + vsrc, vdst0);
  __syncthreads();

  for (int tt = 0; tt < 2048; tt += 32) {
    const int cur = (tt >> 5) & 1;
    // prefetch next tile into other buffer (wrap on last iter: harmless)
    const int tn = (tt + 32) & 2047;
    if (isK) stage16(Kb + (size_t)tn*64 + ksrc, cur ? kdst0 : kdst1);
    else     stage16(Vb + vsrc + tn,            cur ? vdst0 : vdst1);

    // K and V fragments from LDS (shared by all q-sets)
    const u16* Kc = Ks[cur];
    const u16* Vc = Vs[cur];
    short8 kc0 = *(const short8*)&Kc[kro0];
    short8 kc1 = *(const short8*)&Kc[kro1];
    short8 kc2 = *(const short8*)&Kc[kro2];
    short8 kc3 = *(const short8*)&Kc[kro3];
    short8 vv0 = *(const short8*)&Vc[0*512 + vro];
    short8 vv1 = *(const short8*)&Vc[1*512 + vro];
    short8 vv2 = *(const short8*)&Vc[2*512 + vro];
    short8 vv3 = *(const short8*)&Vc[3*512 + vro];

    #pragma unroll
    for (int qs = 0; qs < 4; qs++) {
      f32x4 sl = {0.f,0.f,0.f,0.f}, sh = {0.f,0.f,0.f,0.f};
      sl = __builtin_amdgcn_mfma_f32_16x16x32_bf16(kc0, qa[qs],  sl, 0, 0, 0);
      sl = __builtin_amdgcn_mfma_f32_16x16x32_bf16(kc1, qb_[qs], sl, 0, 0, 0);
      sh = __builtin_amdgcn_mfma_f32_16x16x32_bf16(kc2, qa[qs],  sh, 0, 0, 0);
      sh = __builtin_amdgcn_mfma_f32_16x16x32_bf16(kc3, qb_[qs], sh, 0, 0, 0);
      // exp2 (Q pre-scaled; |scores| small so no max subtraction)
      u16x4 lo, hi;
      #pragma unroll
      for (int r = 0; r < 4; r++) {
        lo[r] = f2bf(__builtin_amdgcn_exp2f(sl[r]));
        hi[r] = f2bf(__builtin_amdgcn_exp2f(sh[r]));
      }
      // P^T redistribute via per-wave LDS round-trip (80B rows, alternating buf)
      u16* P = (qs & 1) ? P1 : P0;
      *(u16x4*)&P[qr*40 + g*4]      = lo;    // t = 4g..4g+3
      *(u16x4*)&P[qr*40 + 16 + g*4] = hi;    // t = 16+4g..+3
      short8 bp = *(const short8*)&P[qr*40 + g*8];   // t = 8g..8g+7, q = qr
      // denominator via MFMA (ones A-frag): every lane gets l for col qr
      ol[qs] = __builtin_amdgcn_mfma_f32_16x16x32_bf16(ones, bp, ol[qs], 0, 0, 0);
      // PV: heads^T[dk][q] += V^T[dk][t] . P^T[t][q]
      o[qs][0] = __builtin_amdgcn_mfma_f32_16x16x32_bf16(vv0, bp, o[qs][0], 0, 0, 0);
      o[qs][1] = __builtin_amdgcn_mfma_f32_16x16x32_bf16(vv1, bp, o[qs][1], 0, 0, 0);
      o[qs][2] = __builtin_amdgcn_mfma_f32_16x16x32_bf16(vv2, bp, o[qs][2], 0, 0, 0);
      o[qs][3] = __builtin_amdgcn_mfma_f32_16x16x32_bf16(vv3, bp, o[qs][3], 0, 0, 0);
    }
    __syncthreads();   // drains vmcnt (staging) + lgkmcnt; next tile ready
  }
  #pragma unroll
  for (int qs = 0; qs < 4; qs++) {
    const float inv = 1.0f / ol[qs][0];
    const size_t base = ((size_t)(b*2048 + q0 + qs*16 + qr))*1024 + h*64;
    #pragma unroll
    for (int d = 0; d < 4; d++) {
      u16x4 v;
      #pragma unroll
      for (int r = 0; r < 4; r++) v[r] = f2bf(o[qs][d][r] * inv);
      *(u16x4*)&cat[base + d*16 + g*4] = v;
    }
  }
}

// ---------------- output projection: f32 out + bias ----------------
__global__ __launch_bounds__(256) void out_gemm_kernel(
    const u16* __restrict__ A, const u16* __restrict__ Bt,
    const float* __restrict__ bias, float* __restrict__ out)
{
  __shared__ __align__(128) u16 As[4096];
  __shared__ __align__(128) u16 Bs[4096];
  const int lane = threadIdx.x & 63, wid = threadIdx.x >> 6;
  const int wr = wid >> 1, wc = wid & 1;
  const int qr = lane & 15, g = lane >> 4;
  const int m0 = blockIdx.y * 128, n0 = blockIdx.x * 128;

  f32x4 acc[4][4];
  gemm_mainloop(A, Bt, m0, n0, As, Bs, acc);

  #pragma unroll
  for (int i = 0; i < 4; i++) {
    const int mrow = m0 + wr*64 + i*16 + g*4;
    #pragma unroll
    for (int j = 0; j < 4; j++) {
      const int n = n0 + wc*64 + j*16 + qr;
      const float bz = bias[n];
      #pragma unroll
      for (int r = 0; r < 4; r++) out[(size_t)(mrow + r)*1024 + n] = acc[i][j][r] + bz;
    }
  }
}

extern "C" void kernel_launch(void* const* d_in, const int* in_sizes, int n_in,
                              void* d_out, int out_size, void* d_ws, size_t ws_size,
                              hipStream_t stream) {
  const float* x  = (const float*)d_in[0];
  const float* Wq = (const float*)d_in[1];
  const float* bq = (const float*)d_in[2];
  const float* Wk = (const float*)d_in[3];
  const float* bk = (const float*)d_in[4];
  const float* Wv = (const float*)d_in[5];
  const float* bv = (const float*)d_in[6];
  const float* Wo = (const float*)d_in[7];
  const float* bo = (const float*)d_in[8];
  float* out = (float*)d_out;
  char* ws = (char*)d_ws;

  // workspace layout (bytes): xb 16M (reused as cat) | Wt 6M | Wot 2M | Q 16M | K 16M | Vt 16M
  u16* xb  = (u16*)(ws);
  u16* Wt  = (u16*)(ws + 16777216);
  u16* Wot = (u16*)(ws + 23068672);
  u16* Qb  = (u16*)(ws + 25165824);
  u16* Kb  = (u16*)(ws + 41943040);
  u16* Vt  = (u16*)(ws + 58720256);
  u16* cat = xb;  // xb dead after qkv_gemm; attn writes cat there

  cvt_kernel<<<8192, 256, 0, stream>>>(x, Wq, Wk, Wv, Wo, xb, Wt, Wot);
  qkv_gemm_kernel<<<dim3(8, 64, 3), 256, 0, stream>>>(xb, Wt, bq, bk, bv, Qb, Kb, Vt);
  attn_kernel<<<256, 512, 0, stream>>>(Qb, Kb, Vt, cat);
  out_gemm_kernel<<<dim3(8, 64), 256, 0, stream>>>(cat, Wot, bo, out);
}